// Round 12
// baseline (475.371 us; speedup 1.0000x reference)
//
#include <hip/hip_runtime.h>

#define N_NODES 50000
#define N_EDGES 800000
#define NODE_FEAT 176
#define HIDDEN 64
#define LN_EPS 1e-5f
#define SCAN_NB 49   // ceil(50000/1024)
#define NBC 64       // CSR-build blocks
#define CHUNK 12500  // edges per CSR block (64*12500 = 800000)
#define RNG 12500    // dst range per sub-pass (4*12500 = 50000)

typedef short bf16x8 __attribute__((ext_vector_type(8)));
typedef float f32x4 __attribute__((ext_vector_type(4)));
typedef long long ll2 __attribute__((ext_vector_type(2)));

__device__ __forceinline__ unsigned short f2bf(float f) {
    unsigned int u = __float_as_uint(f);
    u += 0x7FFFu + ((u >> 16) & 1u);  // round-to-nearest-even
    return (unsigned short)(u >> 16);
}
__device__ __forceinline__ int pack2(float lo, float hi) {
    return (int)(((unsigned)f2bf(hi) << 16) | (unsigned)f2bf(lo));
}
__device__ __forceinline__ float bf2f(unsigned short s) {
    return __uint_as_float(((unsigned int)s) << 16);
}

#if __has_builtin(__builtin_amdgcn_cvt_pk_fp8_f32) && __has_builtin(__builtin_amdgcn_cvt_f32_fp8)
#define HW_FP8 1
#endif

__device__ __forceinline__ unsigned char f2fp8(float f) {
#ifdef HW_FP8
    return (unsigned char)(__builtin_amdgcn_cvt_pk_fp8_f32(f, f, 0, false) & 0xff);
#else
    unsigned u = __float_as_uint(f);
    unsigned s = (u >> 24) & 0x80u;
    float a = fabsf(f);
    if (a >= 448.f) return (unsigned char)(s | 0x7E);
    if (a < 0.0078125f) {
        int m = (int)fmaf(a, 512.0f, 0.5f);
        return (unsigned char)(s | (m > 7 ? 7 : m));
    }
    unsigned au = u & 0x7fffffffu;
    au += 0x7ffffu + ((au >> 20) & 1u);
    int e8 = (int)(au >> 23) - 120;
    if (e8 <= 0) {
        int m = (int)fmaf(__uint_as_float(au), 512.0f, 0.5f);
        return (unsigned char)(s | (m > 7 ? 7 : m));
    }
    if (e8 > 15) return (unsigned char)(s | 0x7E);
    return (unsigned char)(s | (e8 << 3) | ((au >> 20) & 7));
#endif
}
__device__ __forceinline__ float fp82f(int b) {
#ifdef HW_FP8
    return __builtin_amdgcn_cvt_f32_fp8(b & 0xff, 0);
#else
    int s = (b >> 7) & 1, e = (b >> 3) & 15, m = b & 7;
    float v = e ? __uint_as_float(((unsigned)(e + 120) << 23) | ((unsigned)m << 20))
                : (float)m * 0.001953125f;
    return s ? -v : v;
#endif
}

__device__ __forceinline__ float wave_sum64(float v) {
#pragma unroll
    for (int o = 32; o > 0; o >>= 1) v += __shfl_xor(v, o);
    return v;
}
__device__ __forceinline__ float sum16(float v) {
#pragma unroll
    for (int o = 8; o > 0; o >>= 1) v += __shfl_xor(v, o);
    return v;
}

// ---------------- weight prep ----------------
__global__ __launch_bounds__(256) void k_wprep(const float* __restrict__ in_w,
                                               const float* __restrict__ w1,
                                               const float* __restrict__ w2,
                                               unsigned short* __restrict__ fin,
                                               unsigned short* __restrict__ f1,
                                               unsigned short* __restrict__ f2) {
    int t = blockIdx.x * 256 + threadIdx.x;
    if (t < 12288) {  // in_w: [176->192 pad][64]
        int e = t;
        int r = e & 7, lane = (e >> 3) & 63, j = (e >> 9) & 3, s = e >> 11;
        int k = s * 32 + ((lane >> 4) << 3) + r;
        int n = (j << 4) + (lane & 15);
        fin[e] = (k < NODE_FEAT) ? f2bf(in_w[k * 64 + n]) : (unsigned short)0;
    } else if (t < 12288 + 32768) {  // w1: 4 layers x [64][128]
        int e = t - 12288;
        int L = e >> 13, e2 = e & 8191;
        int r = e2 & 7, lane = (e2 >> 3) & 63, j = (e2 >> 9) & 7, s = (e2 >> 12) & 1;
        int k = s * 32 + ((lane >> 4) << 3) + r;
        int n = (j << 4) + (lane & 15);
        f1[e] = f2bf(w1[L * 8192 + k * 128 + n]);
    } else if (t < 12288 + 32768 + 32768) {  // w2: 4 layers x [128][64]
        int e = t - 45056;
        int L = e >> 13, e2 = e & 8191;
        int r = e2 & 7, lane = (e2 >> 3) & 63, j = (e2 >> 9) & 3, s = (e2 >> 11) & 3;
        int k = s * 32 + ((lane >> 4) << 3) + r;
        int n = (j << 4) + (lane & 15);
        f2[e] = f2bf(w2[L * 8192 + k * 64 + n]);
    }
}

// ---------------- input projection via MFMA -> bf16 + fp8 h ----------------
__global__ __launch_bounds__(256) void k_inproj_mfma(const float* __restrict__ x,
                                                     const unsigned short* __restrict__ wfrag,
                                                     const float* __restrict__ in_b,
                                                     unsigned short* __restrict__ hb,
                                                     unsigned char* __restrict__ hf8) {
    __shared__ unsigned short lw[12288];  // 24 KB
    const int tid = threadIdx.x;
    {
        const bf16x8* src = (const bf16x8*)wfrag;
        bf16x8* dst = (bf16x8*)lw;
        for (int i = tid; i < 1536; i += 256) dst[i] = src[i];
    }
    __syncthreads();
    const int wv = tid >> 6, lane = tid & 63;
    const int lrow = lane & 15, lgrp = lane >> 4;
    float ib[4];
#pragma unroll
    for (int j = 0; j < 4; ++j) ib[j] = in_b[16 * j + lrow];
    const int nwaves = gridDim.x * 4;
    for (int tile = blockIdx.x * 4 + wv; tile < 3125; tile += nwaves) {
        const int m0 = tile * 16;
        f32x4 acc[4];
#pragma unroll
        for (int j = 0; j < 4; ++j) acc[j] = (f32x4){ib[j], ib[j], ib[j], ib[j]};
#pragma unroll
        for (int s = 0; s < 6; ++s) {
            const int kbase = s * 32 + lgrp * 8;
            bf16x8 a;
            if (kbase < NODE_FEAT) {
                const float* p = x + (size_t)(m0 + lrow) * NODE_FEAT + kbase;
                float4 fa = *(const float4*)p;
                float4 fb = *(const float4*)(p + 4);
                a[0] = (short)f2bf(fa.x); a[1] = (short)f2bf(fa.y);
                a[2] = (short)f2bf(fa.z); a[3] = (short)f2bf(fa.w);
                a[4] = (short)f2bf(fb.x); a[5] = (short)f2bf(fb.y);
                a[6] = (short)f2bf(fb.z); a[7] = (short)f2bf(fb.w);
            } else {
                a = (bf16x8){0, 0, 0, 0, 0, 0, 0, 0};
            }
#pragma unroll
            for (int j = 0; j < 4; ++j) {
                bf16x8 b = *(const bf16x8*)&lw[((s * 4 + j) * 64 + lane) * 8];
                acc[j] = __builtin_amdgcn_mfma_f32_16x16x32_bf16(a, b, acc[j], 0, 0, 0);
            }
        }
#pragma unroll
        for (int j = 0; j < 4; ++j) {
            const int col = 16 * j + lrow;
#pragma unroll
            for (int r = 0; r < 4; ++r) {
                const int node = m0 + lgrp * 4 + r;
                float v = acc[j][r];
                __builtin_nontemporal_store(f2bf(v), &hb[(size_t)node * 64 + col]);
                hf8[(size_t)node * 64 + col] = f2fp8(v);  // cached: gather table
            }
        }
    }
}

// ---------------- CSR build (LDS histograms, no global atomics) ----------------
// k_cnt: block b counts its 12500-edge chunk into cmat[b][dst] via 4 dst-range
// sub-passes with a 50KB LDS histogram.
__global__ __launch_bounds__(256) void k_cnt(const int* __restrict__ ei,
                                             unsigned short* __restrict__ cmat) {
    __shared__ int h[RNG];  // 50 KB
    const int b = blockIdx.x, t = threadIdx.x;
    const int e0 = b * CHUNK;
    unsigned short* crow = cmat + (size_t)b * N_NODES;
    for (int r = 0; r < 4; ++r) {
        const int lo = r * RNG;
        for (int i = t; i < RNG; i += 256) h[i] = 0;
        __syncthreads();
        for (int i = t; i < CHUNK; i += 256) {
            int d = ei[N_EDGES + e0 + i];
            unsigned dr = (unsigned)(d - lo);
            if (dr < (unsigned)RNG) atomicAdd(&h[dr], 1);
        }
        __syncthreads();
        for (int i = t; i < RNG; i += 256) crow[lo + i] = (unsigned short)h[i];
        __syncthreads();
    }
}

// scan_part: per-dst totals from cmat + per-scanblock sums
__global__ __launch_bounds__(256) void k_scan_part(const unsigned short* __restrict__ cmat,
                                                   int* __restrict__ cnttot,
                                                   int* __restrict__ blksum) {
    const int b = blockIdx.x, t = threadIdx.x;
    const int base = b * 1024 + t * 4;
    int c[4] = {0, 0, 0, 0};
    for (int bb = 0; bb < NBC; ++bb) {
        const unsigned short* row = cmat + (size_t)bb * N_NODES;
#pragma unroll
        for (int i = 0; i < 4; ++i) {
            int idx = base + i;
            if (idx < N_NODES) c[i] += row[idx];
        }
    }
#pragma unroll
    for (int i = 0; i < 4; ++i) {
        int idx = base + i;
        if (idx < N_NODES) cnttot[idx] = c[i];
    }
    int s = c[0] + c[1] + c[2] + c[3];
#pragma unroll
    for (int o = 32; o > 0; o >>= 1) s += __shfl_xor(s, o);
    __shared__ int wt[4];
    if ((t & 63) == 0) wt[t >> 6] = s;
    __syncthreads();
    if (t == 0) blksum[b] = wt[0] + wt[1] + wt[2] + wt[3];
}

// scan_add: row_ptr (exclusive scan of totals, folded top scan) + omat emission
__global__ __launch_bounds__(256) void k_scan_add(const int* __restrict__ cnttot,
                                                  const int* __restrict__ blksum,
                                                  const unsigned short* __restrict__ cmat,
                                                  int* __restrict__ row_ptr,
                                                  int* __restrict__ omat) {
    const int b = blockIdx.x, t = threadIdx.x;
    __shared__ int boff_s;
    if (t < 64) {
        int v = (t < SCAN_NB) ? blksum[t] : 0;
        int incl = v;
#pragma unroll
        for (int o = 1; o < 64; o <<= 1) {
            int u = __shfl_up(incl, o);
            if (t >= o) incl += u;
        }
        if (t == b) boff_s = incl - v;
        if (b == 0 && t == 63) row_ptr[N_NODES] = incl;
    }
    __syncthreads();
    const int base = b * 1024 + t * 4;
    int c[4];
    int tsum = 0;
#pragma unroll
    for (int i = 0; i < 4; ++i) {
        int idx = base + i;
        c[i] = (idx < N_NODES) ? cnttot[idx] : 0;
        tsum += c[i];
    }
    int incl = tsum;
#pragma unroll
    for (int o = 1; o < 64; o <<= 1) {
        int u = __shfl_up(incl, o);
        if ((t & 63) >= o) incl += u;
    }
    __shared__ int wt[4];
    const int wv = t >> 6;
    if ((t & 63) == 63) wt[wv] = incl;
    __syncthreads();
    int run = boff_s + (incl - tsum);
    for (int w = 0; w < wv; ++w) run += wt[w];
    int rp[4];
#pragma unroll
    for (int i = 0; i < 4; ++i) {
        int idx = base + i;
        rp[i] = run;
        if (idx < N_NODES) row_ptr[idx] = run;
        run += c[i];
    }
    int accq[4] = {0, 0, 0, 0};
    for (int bb = 0; bb < NBC; ++bb) {
        const size_t ro = (size_t)bb * N_NODES;
#pragma unroll
        for (int i = 0; i < 4; ++i) {
            int idx = base + i;
            if (idx < N_NODES) {
                omat[ro + idx] = rp[i] + accq[i];
                accq[i] += cmat[ro + idx];
            }
        }
    }
}

// scatter2: LDS cursor per dst-range; pos = omat[b][d] + local_rank; no global atomics
__global__ __launch_bounds__(256) void k_scatter2(const int* __restrict__ ei,
                                                  const float4* __restrict__ ea,
                                                  const int* __restrict__ omat,
                                                  int4* __restrict__ rec) {
    __shared__ int h[RNG];  // 50 KB cursors
    const int b = blockIdx.x, t = threadIdx.x;
    const int e0 = b * CHUNK;
    const int* om = omat + (size_t)b * N_NODES;
    for (int r = 0; r < 4; ++r) {
        const int lo = r * RNG;
        for (int i = t; i < RNG; i += 256) h[i] = 0;
        __syncthreads();
        for (int i = t; i < CHUNK; i += 256) {
            const int e = e0 + i;
            int d = ei[N_EDGES + e];
            unsigned dr = (unsigned)(d - lo);
            if (dr < (unsigned)RNG) {
                int lr = atomicAdd(&h[dr], 1);
                float4 a = ea[e];
                int4 rr;
                rr.x = pack2(a.x, a.y);
                rr.y = pack2(a.z, a.w);
                rr.z = ei[e];
                rr.w = 0;
                rec[om[d] + lr] = rr;
            }
        }
        __syncthreads();
    }
}

// ---------------- gather + aggregate (fp8 gathers, SW-pipelined rec loads) ----------------
__global__ __launch_bounds__(256) void k_aggr(const unsigned short* __restrict__ hb_in,
                                              const unsigned char* __restrict__ hf8_in,
                                              unsigned short* __restrict__ zb,
                                              const int* __restrict__ row_ptr,
                                              const int4* __restrict__ rec,
                                              const float* __restrict__ ew,
                                              const float* __restrict__ eb) {
    const int wv = threadIdx.x >> 6, lane = threadIdx.x & 63;
    const int node = blockIdx.x * 4 + wv;  // 12500*4 = 50000 exact
    const float ew0 = ew[0 * 64 + lane], ew1 = ew[1 * 64 + lane];
    const float ew2 = ew[2 * 64 + lane], ew3 = ew[3 * 64 + lane];
    const float ebl = eb[lane];
    const int beg = __builtin_amdgcn_readfirstlane(row_ptr[node]);
    const int end = __builtin_amdgcn_readfirstlane(row_ptr[node + 1]);
    float acc = bf2f(__builtin_nontemporal_load(&hb_in[(size_t)node * 64 + lane]));
    const int nb = (end - beg) >> 3;  // full 8-batches
    int i = beg;
    ll2 ra[8];
    if (nb > 0) {
#pragma unroll
        for (int t = 0; t < 8; ++t)
            ra[t] = __builtin_nontemporal_load((const ll2*)(rec + i + t));
    }
    for (int k = 0; k < nb; ++k) {
        ll2 rb[8];
        if (k + 1 < nb) {
#pragma unroll
            for (int t = 0; t < 8; ++t)
                rb[t] = __builtin_nontemporal_load((const ll2*)(rec + i + 8 + t));
        }
        int d0[8], d1[8], sx[8];
#pragma unroll
        for (int t = 0; t < 8; ++t) {
            d0[t] = __builtin_amdgcn_readfirstlane((int)(ra[t][0] & 0xffffffffLL));
            d1[t] = __builtin_amdgcn_readfirstlane((int)(ra[t][0] >> 32));
            sx[t] = __builtin_amdgcn_readfirstlane((int)(ra[t][1] & 0xffffffffLL));
        }
        float gg[8];
#pragma unroll
        for (int t = 0; t < 8; ++t)
            gg[t] = fp82f(hf8_in[((size_t)sx[t] << 6) + lane]);
#pragma unroll
        for (int t = 0; t < 8; ++t) {
            float a0 = __uint_as_float((unsigned)d0[t] << 16);
            float a1 = __uint_as_float((unsigned)d0[t] & 0xffff0000u);
            float a2 = __uint_as_float((unsigned)d1[t] << 16);
            float a3 = __uint_as_float((unsigned)d1[t] & 0xffff0000u);
            float v = fmaf(a0, ew0, fmaf(a1, ew1, fmaf(a2, ew2, fmaf(a3, ew3, ebl))));
            acc += fmaxf(v + gg[t], 0.0f);
        }
        if (k + 1 < nb) {
#pragma unroll
            for (int t = 0; t < 8; ++t) ra[t] = rb[t];
        }
        i += 8;
    }
    if (i < end) {  // masked tail (1..7), clamped loads
        const int n = end - i;
        int d0[8], d1[8], sx[8];
#pragma unroll
        for (int t = 0; t < 8; ++t) {
            int idx = i + ((t < n) ? t : (n - 1));
            ll2 r = __builtin_nontemporal_load((const ll2*)(rec + idx));
            d0[t] = __builtin_amdgcn_readfirstlane((int)(r[0] & 0xffffffffLL));
            d1[t] = __builtin_amdgcn_readfirstlane((int)(r[0] >> 32));
            sx[t] = __builtin_amdgcn_readfirstlane((int)(r[1] & 0xffffffffLL));
        }
        float gg[8];
#pragma unroll
        for (int t = 0; t < 8; ++t)
            gg[t] = fp82f(hf8_in[((size_t)sx[t] << 6) + lane]);
#pragma unroll
        for (int t = 0; t < 8; ++t) {
            float m = (t < n) ? 1.0f : 0.0f;
            float a0 = __uint_as_float((unsigned)d0[t] << 16);
            float a1 = __uint_as_float((unsigned)d0[t] & 0xffff0000u);
            float a2 = __uint_as_float((unsigned)d1[t] << 16);
            float a3 = __uint_as_float((unsigned)d1[t] & 0xffff0000u);
            float v = fmaf(a0, ew0, fmaf(a1, ew1, fmaf(a2, ew2, fmaf(a3, ew3, ebl))));
            acc += m * fmaxf(v + gg[t], 0.0f);
        }
    }
    __builtin_nontemporal_store(f2bf(acc), &zb[(size_t)node * 64 + lane]);
}

// ---------------- MLP + LN + relu via MFMA ----------------
__global__ __launch_bounds__(256) void k_mlp_mfma(const unsigned short* __restrict__ zb,
                                                  unsigned short* __restrict__ hb_out,
                                                  unsigned char* __restrict__ hf8_out,
                                                  const unsigned short* __restrict__ f1,
                                                  const unsigned short* __restrict__ f2,
                                                  const float* __restrict__ b1,
                                                  const float* __restrict__ b2,
                                                  const float* __restrict__ lng,
                                                  const float* __restrict__ lnb) {
    __shared__ unsigned short w1f[8192];
    __shared__ unsigned short w2f[8192];
    __shared__ unsigned short z1s[4][2048];
    const int tid = threadIdx.x;
    {
        const bf16x8* s1 = (const bf16x8*)f1;
        const bf16x8* s2 = (const bf16x8*)f2;
        bf16x8* d1 = (bf16x8*)w1f;
        bf16x8* d2 = (bf16x8*)w2f;
        for (int i = tid; i < 1024; i += 256) { d1[i] = s1[i]; d2[i] = s2[i]; }
    }
    __syncthreads();
    const int wv = tid >> 6, lane = tid & 63;
    const int lrow = lane & 15, lgrp = lane >> 4;
    unsigned short* zs = z1s[wv];
    float bb1[8], bb2[4], g4[4], be4[4];
#pragma unroll
    for (int j = 0; j < 8; ++j) bb1[j] = b1[16 * j + lrow];
#pragma unroll
    for (int j = 0; j < 4; ++j) {
        bb2[j] = b2[16 * j + lrow];
        g4[j] = lng[16 * j + lrow];
        be4[j] = lnb[16 * j + lrow];
    }
    const int nwaves = gridDim.x * 4;
    for (int tile = blockIdx.x * 4 + wv; tile < 3125; tile += nwaves) {
        const int m0 = tile * 16;
        f32x4 acc1[8];
#pragma unroll
        for (int j = 0; j < 8; ++j) acc1[j] = (f32x4){bb1[j], bb1[j], bb1[j], bb1[j]};
#pragma unroll
        for (int s = 0; s < 2; ++s) {
            const int kbase = s * 32 + lgrp * 8;
            bf16x8 a = *(const bf16x8*)&zb[(size_t)(m0 + lrow) * 64 + kbase];
#pragma unroll
            for (int j = 0; j < 8; ++j) {
                bf16x8 b = *(const bf16x8*)&w1f[((s * 8 + j) * 64 + lane) * 8];
                acc1[j] = __builtin_amdgcn_mfma_f32_16x16x32_bf16(a, b, acc1[j], 0, 0, 0);
            }
        }
#pragma unroll
        for (int j = 0; j < 8; ++j) {
            const int col = 16 * j + lrow;
#pragma unroll
            for (int r = 0; r < 4; ++r) {
                const int row = lgrp * 4 + r;
                const int idx = (row * 128 + col) ^ ((row & 7) << 3);
                zs[idx] = f2bf(fmaxf(acc1[j][r], 0.0f));
            }
        }
        f32x4 acc2[4];
#pragma unroll
        for (int j = 0; j < 4; ++j) acc2[j] = (f32x4){bb2[j], bb2[j], bb2[j], bb2[j]};
#pragma unroll
        for (int s = 0; s < 4; ++s) {
            const int kbase = s * 32 + lgrp * 8;
            const int idx = (lrow * 128 + kbase) ^ ((lrow & 7) << 3);
            bf16x8 a = *(const bf16x8*)&zs[idx];
#pragma unroll
            for (int j = 0; j < 4; ++j) {
                bf16x8 b = *(const bf16x8*)&w2f[((s * 4 + j) * 64 + lane) * 8];
                acc2[j] = __builtin_amdgcn_mfma_f32_16x16x32_bf16(a, b, acc2[j], 0, 0, 0);
            }
        }
#pragma unroll
        for (int r = 0; r < 4; ++r) {
            float sum = acc2[0][r] + acc2[1][r] + acc2[2][r] + acc2[3][r];
            sum = sum16(sum);
            const float mu = sum * (1.0f / 64.0f);
            float sq = 0.0f;
#pragma unroll
            for (int j = 0; j < 4; ++j) {
                float d = acc2[j][r] - mu;
                sq = fmaf(d, d, sq);
            }
            sq = sum16(sq);
            const float rstd = rsqrtf(sq * (1.0f / 64.0f) + LN_EPS);
            const int node = m0 + lgrp * 4 + r;
#pragma unroll
            for (int j = 0; j < 4; ++j) {
                const int col = 16 * j + lrow;
                float d = acc2[j][r] - mu;
                float hn = fmaxf(fmaf(g4[j] * d, rstd, be4[j]), 0.0f);
                __builtin_nontemporal_store(f2bf(hn), &hb_out[(size_t)node * 64 + col]);
                hf8_out[(size_t)node * 64 + col] = f2fp8(hn);
            }
        }
    }
}

// ---------------- pool (partials, no atomics) + regressor ----------------
__global__ __launch_bounds__(256) void k_pool(const unsigned short* __restrict__ hb,
                                              float* __restrict__ gpart) {
    __shared__ float red[256];
    const int tid = threadIdx.x;
    const int lane = tid & 63;
    float part = 0.0f;
    for (int i = blockIdx.x * 4 + (tid >> 6); i < N_NODES; i += gridDim.x * 4)
        part += bf2f(hb[(size_t)i * 64 + lane]);
    red[tid] = part;
    __syncthreads();
    if (tid < 64) {
        gpart[blockIdx.x * 64 + tid] = red[tid] + red[tid + 64] + red[tid + 128] + red[tid + 192];
    }
}

__global__ __launch_bounds__(64) void k_reg(const float* __restrict__ gpart,
                                            const float* __restrict__ w1,
                                            const float* __restrict__ b1,
                                            const float* __restrict__ w2,
                                            const float* __restrict__ b2,
                                            float* __restrict__ out) {
    const int j = threadIdx.x;
    float gj = 0.0f;
    for (int b = 0; b < 256; ++b) gj += gpart[b * 64 + j];
    __shared__ float gs[64];
    gs[j] = gj;
    __syncthreads();
    const int jm = j & 31;
    float acc = b1[jm];
#pragma unroll 8
    for (int k = 0; k < 64; ++k) {
        float gk = gs[k];
        acc = fmaf(gk, w1[k * 32 + jm], acc);
    }
    float contrib = (j < 32) ? fmaxf(acc, 0.0f) * w2[jm] : 0.0f;
    float s = wave_sum64(contrib);
    if (j == 0) out[0] = s + b2[0];
}

extern "C" void kernel_launch(void* const* d_in, const int* in_sizes, int n_in,
                              void* d_out, int out_size, void* d_ws, size_t ws_size,
                              hipStream_t stream) {
    const float* x      = (const float*)d_in[0];
    const int*   ei     = (const int*)d_in[1];
    const float* ea     = (const float*)d_in[2];
    const float* in_w   = (const float*)d_in[3];
    const float* in_b   = (const float*)d_in[4];
    const float* edge_w = (const float*)d_in[5];
    const float* edge_b = (const float*)d_in[6];
    const float* mlp_w1 = (const float*)d_in[7];
    const float* mlp_b1 = (const float*)d_in[8];
    const float* mlp_w2 = (const float*)d_in[9];
    const float* mlp_b2 = (const float*)d_in[10];
    const float* ln_g   = (const float*)d_in[11];
    const float* ln_b   = (const float*)d_in[12];
    const float* reg_w1 = (const float*)d_in[13];
    const float* reg_b1 = (const float*)d_in[14];
    const float* reg_w2 = (const float*)d_in[15];
    const float* reg_b2 = (const float*)d_in[16];

    char* ws = (char*)d_ws;
    unsigned short* hb0     = (unsigned short*)ws; ws += (size_t)N_NODES * 64 * 2;
    unsigned short* hb1     = (unsigned short*)ws; ws += (size_t)N_NODES * 64 * 2;
    unsigned short* zb      = (unsigned short*)ws; ws += (size_t)N_NODES * 64 * 2;
    unsigned char*  hf8_0   = (unsigned char*)ws;  ws += (size_t)N_NODES * 64;
    unsigned char*  hf8_1   = (unsigned char*)ws;  ws += (size_t)N_NODES * 64;
    int4*           rec     = (int4*)ws;           ws += (size_t)N_EDGES * 16;
    unsigned short* fin     = (unsigned short*)ws; ws += 12288 * 2;
    unsigned short* f1      = (unsigned short*)ws; ws += 32768 * 2;
    unsigned short* f2      = (unsigned short*)ws; ws += 32768 * 2;
    unsigned short* cmat    = (unsigned short*)ws; ws += (size_t)NBC * N_NODES * 2;
    int*            omat    = (int*)ws;            ws += (size_t)NBC * N_NODES * 4;
    int*            row_ptr = (int*)ws;            ws += (size_t)(N_NODES + 1) * 4;
    int*            cnt     = (int*)ws;            ws += (size_t)N_NODES * 4;
    int*            blksum  = (int*)ws;            ws += SCAN_NB * 4;
    float*          gpart   = (float*)ws;          ws += 256 * 64 * 4;
    float*          outf    = (float*)d_out;

    k_wprep<<<304, 256, 0, stream>>>(in_w, mlp_w1, mlp_w2, fin, f1, f2);

    k_cnt<<<NBC, 256, 0, stream>>>(ei, cmat);
    k_scan_part<<<SCAN_NB, 256, 0, stream>>>(cmat, cnt, blksum);
    k_scan_add<<<SCAN_NB, 256, 0, stream>>>(cnt, blksum, cmat, row_ptr, omat);
    k_scatter2<<<NBC, 256, 0, stream>>>(ei, (const float4*)ea, omat, rec);

    k_inproj_mfma<<<512, 256, 0, stream>>>(x, fin, in_b, hb0, hf8_0);

    unsigned short* hbA = hb0;
    unsigned short* hbB = hb1;
    unsigned char*  hfA = hf8_0;
    unsigned char*  hfB = hf8_1;
    for (int l = 0; l < 4; ++l) {
        k_aggr<<<N_NODES / 4, 256, 0, stream>>>(hbA, hfA, zb, row_ptr, rec,
                                                edge_w + l * 4 * 64,
                                                edge_b + l * 64);
        k_mlp_mfma<<<768, 256, 0, stream>>>(zb, hbB, hfB,
                                            f1 + l * 8192, f2 + l * 8192,
                                            mlp_b1 + l * 128, mlp_b2 + l * 64,
                                            ln_g + l * 64, ln_b + l * 64);
        unsigned short* tb = hbA; hbA = hbB; hbB = tb;
        unsigned char*  tf = hfA; hfA = hfB; hfB = tf;
    }

    k_pool<<<256, 256, 0, stream>>>(hbA, gpart);
    k_reg<<<1, 64, 0, stream>>>(gpart, reg_w1, reg_b1, reg_w2, reg_b2, outf);
}

// Round 13
// 329.004 us; speedup vs baseline: 1.4449x; 1.4449x over previous
//
#include <hip/hip_runtime.h>

#define N_NODES 50000
#define N_EDGES 800000
#define NODE_FEAT 176
#define HIDDEN 64
#define LN_EPS 1e-5f
#define SCAN_NB 49   // ceil(50000/1024)
#define NBC 256      // CSR-build blocks (1 per CU)
#define CHUNK 3125   // edges per CSR block (256*3125 = 800000)
#define RNG 12500    // dst range per sub-pass (4*12500 = 50000)

typedef short bf16x8 __attribute__((ext_vector_type(8)));
typedef float f32x4 __attribute__((ext_vector_type(4)));
typedef long long ll2 __attribute__((ext_vector_type(2)));

__device__ __forceinline__ unsigned short f2bf(float f) {
    unsigned int u = __float_as_uint(f);
    u += 0x7FFFu + ((u >> 16) & 1u);  // round-to-nearest-even
    return (unsigned short)(u >> 16);
}
__device__ __forceinline__ int pack2(float lo, float hi) {
    return (int)(((unsigned)f2bf(hi) << 16) | (unsigned)f2bf(lo));
}
__device__ __forceinline__ float bf2f(unsigned short s) {
    return __uint_as_float(((unsigned int)s) << 16);
}

#if __has_builtin(__builtin_amdgcn_cvt_pk_fp8_f32) && __has_builtin(__builtin_amdgcn_cvt_f32_fp8)
#define HW_FP8 1
#endif

__device__ __forceinline__ unsigned char f2fp8(float f) {
#ifdef HW_FP8
    return (unsigned char)(__builtin_amdgcn_cvt_pk_fp8_f32(f, f, 0, false) & 0xff);
#else
    unsigned u = __float_as_uint(f);
    unsigned s = (u >> 24) & 0x80u;
    float a = fabsf(f);
    if (a >= 448.f) return (unsigned char)(s | 0x7E);
    if (a < 0.0078125f) {
        int m = (int)fmaf(a, 512.0f, 0.5f);
        return (unsigned char)(s | (m > 7 ? 7 : m));
    }
    unsigned au = u & 0x7fffffffu;
    au += 0x7ffffu + ((au >> 20) & 1u);
    int e8 = (int)(au >> 23) - 120;
    if (e8 <= 0) {
        int m = (int)fmaf(__uint_as_float(au), 512.0f, 0.5f);
        return (unsigned char)(s | (m > 7 ? 7 : m));
    }
    if (e8 > 15) return (unsigned char)(s | 0x7E);
    return (unsigned char)(s | (e8 << 3) | ((au >> 20) & 7));
#endif
}
__device__ __forceinline__ float fp82f(int b) {
#ifdef HW_FP8
    return __builtin_amdgcn_cvt_f32_fp8(b & 0xff, 0);
#else
    int s = (b >> 7) & 1, e = (b >> 3) & 15, m = b & 7;
    float v = e ? __uint_as_float(((unsigned)(e + 120) << 23) | ((unsigned)m << 20))
                : (float)m * 0.001953125f;
    return s ? -v : v;
#endif
}

__device__ __forceinline__ float wave_sum64(float v) {
#pragma unroll
    for (int o = 32; o > 0; o >>= 1) v += __shfl_xor(v, o);
    return v;
}
__device__ __forceinline__ float sum16(float v) {
#pragma unroll
    for (int o = 8; o > 0; o >>= 1) v += __shfl_xor(v, o);
    return v;
}

// ---------------- weight prep ----------------
__global__ __launch_bounds__(256) void k_wprep(const float* __restrict__ in_w,
                                               const float* __restrict__ w1,
                                               const float* __restrict__ w2,
                                               unsigned short* __restrict__ fin,
                                               unsigned short* __restrict__ f1,
                                               unsigned short* __restrict__ f2) {
    int t = blockIdx.x * 256 + threadIdx.x;
    if (t < 12288) {  // in_w: [176->192 pad][64]
        int e = t;
        int r = e & 7, lane = (e >> 3) & 63, j = (e >> 9) & 3, s = e >> 11;
        int k = s * 32 + ((lane >> 4) << 3) + r;
        int n = (j << 4) + (lane & 15);
        fin[e] = (k < NODE_FEAT) ? f2bf(in_w[k * 64 + n]) : (unsigned short)0;
    } else if (t < 12288 + 32768) {  // w1: 4 layers x [64][128]
        int e = t - 12288;
        int L = e >> 13, e2 = e & 8191;
        int r = e2 & 7, lane = (e2 >> 3) & 63, j = (e2 >> 9) & 7, s = (e2 >> 12) & 1;
        int k = s * 32 + ((lane >> 4) << 3) + r;
        int n = (j << 4) + (lane & 15);
        f1[e] = f2bf(w1[L * 8192 + k * 128 + n]);
    } else if (t < 12288 + 32768 + 32768) {  // w2: 4 layers x [128][64]
        int e = t - 45056;
        int L = e >> 13, e2 = e & 8191;
        int r = e2 & 7, lane = (e2 >> 3) & 63, j = (e2 >> 9) & 3, s = (e2 >> 11) & 3;
        int k = s * 32 + ((lane >> 4) << 3) + r;
        int n = (j << 4) + (lane & 15);
        f2[e] = f2bf(w2[L * 8192 + k * 64 + n]);
    }
}

// ---------------- input projection via MFMA -> bf16 + fp8 h ----------------
__global__ __launch_bounds__(256) void k_inproj_mfma(const float* __restrict__ x,
                                                     const unsigned short* __restrict__ wfrag,
                                                     const float* __restrict__ in_b,
                                                     unsigned short* __restrict__ hb,
                                                     unsigned char* __restrict__ hf8) {
    __shared__ unsigned short lw[12288];  // 24 KB
    const int tid = threadIdx.x;
    {
        const bf16x8* src = (const bf16x8*)wfrag;
        bf16x8* dst = (bf16x8*)lw;
        for (int i = tid; i < 1536; i += 256) dst[i] = src[i];
    }
    __syncthreads();
    const int wv = tid >> 6, lane = tid & 63;
    const int lrow = lane & 15, lgrp = lane >> 4;
    float ib[4];
#pragma unroll
    for (int j = 0; j < 4; ++j) ib[j] = in_b[16 * j + lrow];
    const int nwaves = gridDim.x * 4;
    for (int tile = blockIdx.x * 4 + wv; tile < 3125; tile += nwaves) {
        const int m0 = tile * 16;
        f32x4 acc[4];
#pragma unroll
        for (int j = 0; j < 4; ++j) acc[j] = (f32x4){ib[j], ib[j], ib[j], ib[j]};
#pragma unroll
        for (int s = 0; s < 6; ++s) {
            const int kbase = s * 32 + lgrp * 8;
            bf16x8 a;
            if (kbase < NODE_FEAT) {
                const float* p = x + (size_t)(m0 + lrow) * NODE_FEAT + kbase;
                float4 fa = *(const float4*)p;
                float4 fb = *(const float4*)(p + 4);
                a[0] = (short)f2bf(fa.x); a[1] = (short)f2bf(fa.y);
                a[2] = (short)f2bf(fa.z); a[3] = (short)f2bf(fa.w);
                a[4] = (short)f2bf(fb.x); a[5] = (short)f2bf(fb.y);
                a[6] = (short)f2bf(fb.z); a[7] = (short)f2bf(fb.w);
            } else {
                a = (bf16x8){0, 0, 0, 0, 0, 0, 0, 0};
            }
#pragma unroll
            for (int j = 0; j < 4; ++j) {
                bf16x8 b = *(const bf16x8*)&lw[((s * 4 + j) * 64 + lane) * 8];
                acc[j] = __builtin_amdgcn_mfma_f32_16x16x32_bf16(a, b, acc[j], 0, 0, 0);
            }
        }
#pragma unroll
        for (int j = 0; j < 4; ++j) {
            const int col = 16 * j + lrow;
#pragma unroll
            for (int r = 0; r < 4; ++r) {
                const int node = m0 + lgrp * 4 + r;
                float v = acc[j][r];
                __builtin_nontemporal_store(f2bf(v), &hb[(size_t)node * 64 + col]);
                hf8[(size_t)node * 64 + col] = f2fp8(v);  // cached: gather table
            }
        }
    }
}

// ---------------- CSR build (LDS histograms, no global atomics) ----------------
// k_cnt: block b counts its 3125-edge chunk into cmat[b][dst] via 4 dst-range
// sub-passes with a 50KB LDS histogram.
__global__ __launch_bounds__(256) void k_cnt(const int* __restrict__ ei,
                                             unsigned short* __restrict__ cmat) {
    __shared__ int h[RNG];  // 50 KB
    const int b = blockIdx.x, t = threadIdx.x;
    const int e0 = b * CHUNK;
    unsigned short* crow = cmat + (size_t)b * N_NODES;
    for (int r = 0; r < 4; ++r) {
        const int lo = r * RNG;
        for (int i = t * 4; i < RNG; i += 1024) *(int4*)&h[i] = (int4){0, 0, 0, 0};
        __syncthreads();
        for (int i = t; i < CHUNK; i += 256) {
            int d = ei[N_EDGES + e0 + i];
            unsigned dr = (unsigned)(d - lo);
            if (dr < (unsigned)RNG) atomicAdd(&h[dr], 1);
        }
        __syncthreads();
        for (int i = t * 4; i < RNG; i += 1024) {
            ushort4 v;
            v.x = (unsigned short)h[i];
            v.y = (unsigned short)h[i + 1];
            v.z = (unsigned short)h[i + 2];
            v.w = (unsigned short)h[i + 3];
            *(ushort4*)&crow[lo + i] = v;
        }
        __syncthreads();
    }
}

// scan_part: per-dst totals from cmat + per-scanblock sums (ushort4 loads)
__global__ __launch_bounds__(256) void k_scan_part(const unsigned short* __restrict__ cmat,
                                                   int* __restrict__ cnttot,
                                                   int* __restrict__ blksum) {
    const int b = blockIdx.x, t = threadIdx.x;
    const int base = b * 1024 + t * 4;  // N_NODES % 4 == 0: all-or-none valid
    int c0 = 0, c1 = 0, c2 = 0, c3 = 0;
    if (base < N_NODES) {
        for (int bb = 0; bb < NBC; ++bb) {
            ushort4 v = *(const ushort4*)(cmat + (size_t)bb * N_NODES + base);
            c0 += v.x; c1 += v.y; c2 += v.z; c3 += v.w;
        }
        *(int4*)&cnttot[base] = (int4){c0, c1, c2, c3};
    }
    int s = c0 + c1 + c2 + c3;
#pragma unroll
    for (int o = 32; o > 0; o >>= 1) s += __shfl_xor(s, o);
    __shared__ int wt[4];
    if ((t & 63) == 0) wt[t >> 6] = s;
    __syncthreads();
    if (t == 0) blksum[b] = wt[0] + wt[1] + wt[2] + wt[3];
}

// scan_add: row_ptr (exclusive scan, folded top scan) + omat emission (int4 stores)
__global__ __launch_bounds__(256) void k_scan_add(const int* __restrict__ cnttot,
                                                  const int* __restrict__ blksum,
                                                  const unsigned short* __restrict__ cmat,
                                                  int* __restrict__ row_ptr,
                                                  int* __restrict__ omat) {
    const int b = blockIdx.x, t = threadIdx.x;
    __shared__ int boff_s;
    if (t < 64) {
        int v = (t < SCAN_NB) ? blksum[t] : 0;
        int incl = v;
#pragma unroll
        for (int o = 1; o < 64; o <<= 1) {
            int u = __shfl_up(incl, o);
            if (t >= o) incl += u;
        }
        if (t == b) boff_s = incl - v;
        if (b == 0 && t == 63) row_ptr[N_NODES] = incl;
    }
    __syncthreads();
    const int base = b * 1024 + t * 4;
    const bool ok = base < N_NODES;
    int c[4] = {0, 0, 0, 0};
    if (ok) {
        int4 cv = *(const int4*)&cnttot[base];
        c[0] = cv.x; c[1] = cv.y; c[2] = cv.z; c[3] = cv.w;
    }
    int tsum = c[0] + c[1] + c[2] + c[3];
    int incl = tsum;
#pragma unroll
    for (int o = 1; o < 64; o <<= 1) {
        int u = __shfl_up(incl, o);
        if ((t & 63) >= o) incl += u;
    }
    __shared__ int wt[4];
    const int wv = t >> 6;
    if ((t & 63) == 63) wt[wv] = incl;
    __syncthreads();
    int run = boff_s + (incl - tsum);
    for (int w = 0; w < wv; ++w) run += wt[w];
    int rp[4];
#pragma unroll
    for (int i = 0; i < 4; ++i) {
        rp[i] = run;
        if (ok) row_ptr[base + i] = run;
        run += c[i];
    }
    if (ok) {
        int a0 = 0, a1 = 0, a2 = 0, a3 = 0;
        for (int bb = 0; bb < NBC; ++bb) {
            const size_t ro = (size_t)bb * N_NODES;
            *(int4*)&omat[ro + base] = (int4){rp[0] + a0, rp[1] + a1, rp[2] + a2, rp[3] + a3};
            ushort4 v = *(const ushort4*)(cmat + ro + base);
            a0 += v.x; a1 += v.y; a2 += v.z; a3 += v.w;
        }
    }
}

// scatter2: LDS cursor per dst-range; pos = omat[b][d] + local_rank; no global atomics
__global__ __launch_bounds__(256) void k_scatter2(const int* __restrict__ ei,
                                                  const float4* __restrict__ ea,
                                                  const int* __restrict__ omat,
                                                  int4* __restrict__ rec) {
    __shared__ int h[RNG];  // 50 KB cursors
    const int b = blockIdx.x, t = threadIdx.x;
    const int e0 = b * CHUNK;
    const int* om = omat + (size_t)b * N_NODES;
    for (int r = 0; r < 4; ++r) {
        const int lo = r * RNG;
        for (int i = t * 4; i < RNG; i += 1024) *(int4*)&h[i] = (int4){0, 0, 0, 0};
        __syncthreads();
        for (int i = t; i < CHUNK; i += 256) {
            const int e = e0 + i;
            int d = ei[N_EDGES + e];
            unsigned dr = (unsigned)(d - lo);
            if (dr < (unsigned)RNG) {
                int base = om[d];                // independent of cursor
                float4 a = ea[e];
                int lr = atomicAdd(&h[dr], 1);
                int4 rr;
                rr.x = pack2(a.x, a.y);
                rr.y = pack2(a.z, a.w);
                rr.z = ei[e];
                rr.w = 0;
                rec[base + lr] = rr;
            }
        }
        __syncthreads();
    }
}

// ---------------- gather + aggregate (fp8 gathers, SW-pipelined rec loads) ----------------
__global__ __launch_bounds__(256) void k_aggr(const unsigned short* __restrict__ hb_in,
                                              const unsigned char* __restrict__ hf8_in,
                                              unsigned short* __restrict__ zb,
                                              const int* __restrict__ row_ptr,
                                              const int4* __restrict__ rec,
                                              const float* __restrict__ ew,
                                              const float* __restrict__ eb) {
    const int wv = threadIdx.x >> 6, lane = threadIdx.x & 63;
    const int node = blockIdx.x * 4 + wv;  // 12500*4 = 50000 exact
    const float ew0 = ew[0 * 64 + lane], ew1 = ew[1 * 64 + lane];
    const float ew2 = ew[2 * 64 + lane], ew3 = ew[3 * 64 + lane];
    const float ebl = eb[lane];
    const int beg = __builtin_amdgcn_readfirstlane(row_ptr[node]);
    const int end = __builtin_amdgcn_readfirstlane(row_ptr[node + 1]);
    float acc = bf2f(__builtin_nontemporal_load(&hb_in[(size_t)node * 64 + lane]));
    const int nb = (end - beg) >> 3;  // full 8-batches
    int i = beg;
    ll2 ra[8];
    if (nb > 0) {
#pragma unroll
        for (int t = 0; t < 8; ++t)
            ra[t] = __builtin_nontemporal_load((const ll2*)(rec + i + t));
    }
    for (int k = 0; k < nb; ++k) {
        ll2 rb[8];
        if (k + 1 < nb) {
#pragma unroll
            for (int t = 0; t < 8; ++t)
                rb[t] = __builtin_nontemporal_load((const ll2*)(rec + i + 8 + t));
        }
        int d0[8], d1[8], sx[8];
#pragma unroll
        for (int t = 0; t < 8; ++t) {
            d0[t] = __builtin_amdgcn_readfirstlane((int)(ra[t][0] & 0xffffffffLL));
            d1[t] = __builtin_amdgcn_readfirstlane((int)(ra[t][0] >> 32));
            sx[t] = __builtin_amdgcn_readfirstlane((int)(ra[t][1] & 0xffffffffLL));
        }
        float gg[8];
#pragma unroll
        for (int t = 0; t < 8; ++t)
            gg[t] = fp82f(hf8_in[((size_t)sx[t] << 6) + lane]);
#pragma unroll
        for (int t = 0; t < 8; ++t) {
            float a0 = __uint_as_float((unsigned)d0[t] << 16);
            float a1 = __uint_as_float((unsigned)d0[t] & 0xffff0000u);
            float a2 = __uint_as_float((unsigned)d1[t] << 16);
            float a3 = __uint_as_float((unsigned)d1[t] & 0xffff0000u);
            float v = fmaf(a0, ew0, fmaf(a1, ew1, fmaf(a2, ew2, fmaf(a3, ew3, ebl))));
            acc += fmaxf(v + gg[t], 0.0f);
        }
        if (k + 1 < nb) {
#pragma unroll
            for (int t = 0; t < 8; ++t) ra[t] = rb[t];
        }
        i += 8;
    }
    if (i < end) {  // masked tail (1..7), clamped loads
        const int n = end - i;
        int d0[8], d1[8], sx[8];
#pragma unroll
        for (int t = 0; t < 8; ++t) {
            int idx = i + ((t < n) ? t : (n - 1));
            ll2 r = __builtin_nontemporal_load((const ll2*)(rec + idx));
            d0[t] = __builtin_amdgcn_readfirstlane((int)(r[0] & 0xffffffffLL));
            d1[t] = __builtin_amdgcn_readfirstlane((int)(r[0] >> 32));
            sx[t] = __builtin_amdgcn_readfirstlane((int)(r[1] & 0xffffffffLL));
        }
        float gg[8];
#pragma unroll
        for (int t = 0; t < 8; ++t)
            gg[t] = fp82f(hf8_in[((size_t)sx[t] << 6) + lane]);
#pragma unroll
        for (int t = 0; t < 8; ++t) {
            float m = (t < n) ? 1.0f : 0.0f;
            float a0 = __uint_as_float((unsigned)d0[t] << 16);
            float a1 = __uint_as_float((unsigned)d0[t] & 0xffff0000u);
            float a2 = __uint_as_float((unsigned)d1[t] << 16);
            float a3 = __uint_as_float((unsigned)d1[t] & 0xffff0000u);
            float v = fmaf(a0, ew0, fmaf(a1, ew1, fmaf(a2, ew2, fmaf(a3, ew3, ebl))));
            acc += m * fmaxf(v + gg[t], 0.0f);
        }
    }
    __builtin_nontemporal_store(f2bf(acc), &zb[(size_t)node * 64 + lane]);
}

// ---------------- MLP + LN + relu via MFMA ----------------
__global__ __launch_bounds__(256) void k_mlp_mfma(const unsigned short* __restrict__ zb,
                                                  unsigned short* __restrict__ hb_out,
                                                  unsigned char* __restrict__ hf8_out,
                                                  const unsigned short* __restrict__ f1,
                                                  const unsigned short* __restrict__ f2,
                                                  const float* __restrict__ b1,
                                                  const float* __restrict__ b2,
                                                  const float* __restrict__ lng,
                                                  const float* __restrict__ lnb) {
    __shared__ unsigned short w1f[8192];
    __shared__ unsigned short w2f[8192];
    __shared__ unsigned short z1s[4][2048];
    const int tid = threadIdx.x;
    {
        const bf16x8* s1 = (const bf16x8*)f1;
        const bf16x8* s2 = (const bf16x8*)f2;
        bf16x8* d1 = (bf16x8*)w1f;
        bf16x8* d2 = (bf16x8*)w2f;
        for (int i = tid; i < 1024; i += 256) { d1[i] = s1[i]; d2[i] = s2[i]; }
    }
    __syncthreads();
    const int wv = tid >> 6, lane = tid & 63;
    const int lrow = lane & 15, lgrp = lane >> 4;
    unsigned short* zs = z1s[wv];
    float bb1[8], bb2[4], g4[4], be4[4];
#pragma unroll
    for (int j = 0; j < 8; ++j) bb1[j] = b1[16 * j + lrow];
#pragma unroll
    for (int j = 0; j < 4; ++j) {
        bb2[j] = b2[16 * j + lrow];
        g4[j] = lng[16 * j + lrow];
        be4[j] = lnb[16 * j + lrow];
    }
    const int nwaves = gridDim.x * 4;
    for (int tile = blockIdx.x * 4 + wv; tile < 3125; tile += nwaves) {
        const int m0 = tile * 16;
        f32x4 acc1[8];
#pragma unroll
        for (int j = 0; j < 8; ++j) acc1[j] = (f32x4){bb1[j], bb1[j], bb1[j], bb1[j]};
#pragma unroll
        for (int s = 0; s < 2; ++s) {
            const int kbase = s * 32 + lgrp * 8;
            bf16x8 a = *(const bf16x8*)&zb[(size_t)(m0 + lrow) * 64 + kbase];
#pragma unroll
            for (int j = 0; j < 8; ++j) {
                bf16x8 b = *(const bf16x8*)&w1f[((s * 8 + j) * 64 + lane) * 8];
                acc1[j] = __builtin_amdgcn_mfma_f32_16x16x32_bf16(a, b, acc1[j], 0, 0, 0);
            }
        }
#pragma unroll
        for (int j = 0; j < 8; ++j) {
            const int col = 16 * j + lrow;
#pragma unroll
            for (int r = 0; r < 4; ++r) {
                const int row = lgrp * 4 + r;
                const int idx = (row * 128 + col) ^ ((row & 7) << 3);
                zs[idx] = f2bf(fmaxf(acc1[j][r], 0.0f));
            }
        }
        f32x4 acc2[4];
#pragma unroll
        for (int j = 0; j < 4; ++j) acc2[j] = (f32x4){bb2[j], bb2[j], bb2[j], bb2[j]};
#pragma unroll
        for (int s = 0; s < 4; ++s) {
            const int kbase = s * 32 + lgrp * 8;
            const int idx = (lrow * 128 + kbase) ^ ((lrow & 7) << 3);
            bf16x8 a = *(const bf16x8*)&zs[idx];
#pragma unroll
            for (int j = 0; j < 4; ++j) {
                bf16x8 b = *(const bf16x8*)&w2f[((s * 4 + j) * 64 + lane) * 8];
                acc2[j] = __builtin_amdgcn_mfma_f32_16x16x32_bf16(a, b, acc2[j], 0, 0, 0);
            }
        }
#pragma unroll
        for (int r = 0; r < 4; ++r) {
            float sum = acc2[0][r] + acc2[1][r] + acc2[2][r] + acc2[3][r];
            sum = sum16(sum);
            const float mu = sum * (1.0f / 64.0f);
            float sq = 0.0f;
#pragma unroll
            for (int j = 0; j < 4; ++j) {
                float d = acc2[j][r] - mu;
                sq = fmaf(d, d, sq);
            }
            sq = sum16(sq);
            const float rstd = rsqrtf(sq * (1.0f / 64.0f) + LN_EPS);
            const int node = m0 + lgrp * 4 + r;
#pragma unroll
            for (int j = 0; j < 4; ++j) {
                const int col = 16 * j + lrow;
                float d = acc2[j][r] - mu;
                float hn = fmaxf(fmaf(g4[j] * d, rstd, be4[j]), 0.0f);
                __builtin_nontemporal_store(f2bf(hn), &hb_out[(size_t)node * 64 + col]);
                hf8_out[(size_t)node * 64 + col] = f2fp8(hn);
            }
        }
    }
}

// ---------------- pool (partials, no atomics) + regressor ----------------
__global__ __launch_bounds__(256) void k_pool(const unsigned short* __restrict__ hb,
                                              float* __restrict__ gpart) {
    __shared__ float red[256];
    const int tid = threadIdx.x;
    const int lane = tid & 63;
    float part = 0.0f;
    for (int i = blockIdx.x * 4 + (tid >> 6); i < N_NODES; i += gridDim.x * 4)
        part += bf2f(hb[(size_t)i * 64 + lane]);
    red[tid] = part;
    __syncthreads();
    if (tid < 64) {
        gpart[blockIdx.x * 64 + tid] = red[tid] + red[tid + 64] + red[tid + 128] + red[tid + 192];
    }
}

__global__ __launch_bounds__(64) void k_reg(const float* __restrict__ gpart,
                                            const float* __restrict__ w1,
                                            const float* __restrict__ b1,
                                            const float* __restrict__ w2,
                                            const float* __restrict__ b2,
                                            float* __restrict__ out) {
    const int j = threadIdx.x;
    float gj = 0.0f;
    for (int b = 0; b < 256; ++b) gj += gpart[b * 64 + j];
    __shared__ float gs[64];
    gs[j] = gj;
    __syncthreads();
    const int jm = j & 31;
    float acc = b1[jm];
#pragma unroll 8
    for (int k = 0; k < 64; ++k) {
        float gk = gs[k];
        acc = fmaf(gk, w1[k * 32 + jm], acc);
    }
    float contrib = (j < 32) ? fmaxf(acc, 0.0f) * w2[jm] : 0.0f;
    float s = wave_sum64(contrib);
    if (j == 0) out[0] = s + b2[0];
}

extern "C" void kernel_launch(void* const* d_in, const int* in_sizes, int n_in,
                              void* d_out, int out_size, void* d_ws, size_t ws_size,
                              hipStream_t stream) {
    const float* x      = (const float*)d_in[0];
    const int*   ei     = (const int*)d_in[1];
    const float* ea     = (const float*)d_in[2];
    const float* in_w   = (const float*)d_in[3];
    const float* in_b   = (const float*)d_in[4];
    const float* edge_w = (const float*)d_in[5];
    const float* edge_b = (const float*)d_in[6];
    const float* mlp_w1 = (const float*)d_in[7];
    const float* mlp_b1 = (const float*)d_in[8];
    const float* mlp_w2 = (const float*)d_in[9];
    const float* mlp_b2 = (const float*)d_in[10];
    const float* ln_g   = (const float*)d_in[11];
    const float* ln_b   = (const float*)d_in[12];
    const float* reg_w1 = (const float*)d_in[13];
    const float* reg_b1 = (const float*)d_in[14];
    const float* reg_w2 = (const float*)d_in[15];
    const float* reg_b2 = (const float*)d_in[16];

    char* ws = (char*)d_ws;
    unsigned short* hb0     = (unsigned short*)ws; ws += (size_t)N_NODES * 64 * 2;
    unsigned short* hb1     = (unsigned short*)ws; ws += (size_t)N_NODES * 64 * 2;
    unsigned short* zb      = (unsigned short*)ws; ws += (size_t)N_NODES * 64 * 2;
    unsigned char*  hf8_0   = (unsigned char*)ws;  ws += (size_t)N_NODES * 64;
    unsigned char*  hf8_1   = (unsigned char*)ws;  ws += (size_t)N_NODES * 64;
    int4*           rec     = (int4*)ws;           ws += (size_t)N_EDGES * 16;
    unsigned short* fin     = (unsigned short*)ws; ws += 12288 * 2;
    unsigned short* f1      = (unsigned short*)ws; ws += 32768 * 2;
    unsigned short* f2      = (unsigned short*)ws; ws += 32768 * 2;
    unsigned short* cmat    = (unsigned short*)ws; ws += (size_t)NBC * N_NODES * 2;
    int*            omat    = (int*)ws;            ws += (size_t)NBC * N_NODES * 4;
    int*            row_ptr = (int*)ws;            ws += (size_t)(N_NODES + 1) * 4;
    int*            cnt     = (int*)ws;            ws += (size_t)N_NODES * 4;
    int*            blksum  = (int*)ws;            ws += SCAN_NB * 4;
    float*          gpart   = (float*)ws;          ws += 256 * 64 * 4;
    float*          outf    = (float*)d_out;

    k_wprep<<<304, 256, 0, stream>>>(in_w, mlp_w1, mlp_w2, fin, f1, f2);

    k_cnt<<<NBC, 256, 0, stream>>>(ei, cmat);
    k_scan_part<<<SCAN_NB, 256, 0, stream>>>(cmat, cnt, blksum);
    k_scan_add<<<SCAN_NB, 256, 0, stream>>>(cnt, blksum, cmat, row_ptr, omat);
    k_scatter2<<<NBC, 256, 0, stream>>>(ei, (const float4*)ea, omat, rec);

    k_inproj_mfma<<<512, 256, 0, stream>>>(x, fin, in_b, hb0, hf8_0);

    unsigned short* hbA = hb0;
    unsigned short* hbB = hb1;
    unsigned char*  hfA = hf8_0;
    unsigned char*  hfB = hf8_1;
    for (int l = 0; l < 4; ++l) {
        k_aggr<<<N_NODES / 4, 256, 0, stream>>>(hbA, hfA, zb, row_ptr, rec,
                                                edge_w + l * 4 * 64,
                                                edge_b + l * 64);
        k_mlp_mfma<<<768, 256, 0, stream>>>(zb, hbB, hfB,
                                            f1 + l * 8192, f2 + l * 8192,
                                            mlp_b1 + l * 128, mlp_b2 + l * 64,
                                            ln_g + l * 64, ln_b + l * 64);
        unsigned short* tb = hbA; hbA = hbB; hbB = tb;
        unsigned char*  tf = hfA; hfA = hfB; hfB = tf;
    }

    k_pool<<<256, 256, 0, stream>>>(hbA, gpart);
    k_reg<<<1, 64, 0, stream>>>(gpart, reg_w1, reg_b1, reg_w2, reg_b2, outf);
}

// Round 14
// 276.857 us; speedup vs baseline: 1.7170x; 1.1884x over previous
//
#include <hip/hip_runtime.h>

#define N_NODES 50000
#define N_EDGES 800000
#define NODE_FEAT 176
#define HIDDEN 64
#define LN_EPS 1e-5f
#define SCAN_NB 49  // ceil(50000/1024)

typedef short bf16x8 __attribute__((ext_vector_type(8)));
typedef float f32x4 __attribute__((ext_vector_type(4)));
typedef long long ll2 __attribute__((ext_vector_type(2)));

__device__ __forceinline__ unsigned short f2bf(float f) {
    unsigned int u = __float_as_uint(f);
    u += 0x7FFFu + ((u >> 16) & 1u);  // round-to-nearest-even
    return (unsigned short)(u >> 16);
}
__device__ __forceinline__ int pack2(float lo, float hi) {
    return (int)(((unsigned)f2bf(hi) << 16) | (unsigned)f2bf(lo));
}
__device__ __forceinline__ float bf2f(unsigned short s) {
    return __uint_as_float(((unsigned int)s) << 16);
}

#if __has_builtin(__builtin_amdgcn_cvt_pk_fp8_f32) && __has_builtin(__builtin_amdgcn_cvt_f32_fp8)
#define HW_FP8 1
#endif

__device__ __forceinline__ unsigned char f2fp8(float f) {
#ifdef HW_FP8
    return (unsigned char)(__builtin_amdgcn_cvt_pk_fp8_f32(f, f, 0, false) & 0xff);
#else
    unsigned u = __float_as_uint(f);
    unsigned s = (u >> 24) & 0x80u;
    float a = fabsf(f);
    if (a >= 448.f) return (unsigned char)(s | 0x7E);
    if (a < 0.0078125f) {
        int m = (int)fmaf(a, 512.0f, 0.5f);
        return (unsigned char)(s | (m > 7 ? 7 : m));
    }
    unsigned au = u & 0x7fffffffu;
    au += 0x7ffffu + ((au >> 20) & 1u);
    int e8 = (int)(au >> 23) - 120;
    if (e8 <= 0) {
        int m = (int)fmaf(__uint_as_float(au), 512.0f, 0.5f);
        return (unsigned char)(s | (m > 7 ? 7 : m));
    }
    if (e8 > 15) return (unsigned char)(s | 0x7E);
    return (unsigned char)(s | (e8 << 3) | ((au >> 20) & 7));
#endif
}
__device__ __forceinline__ float fp82f(int b) {
#ifdef HW_FP8
    return __builtin_amdgcn_cvt_f32_fp8(b & 0xff, 0);
#else
    int s = (b >> 7) & 1, e = (b >> 3) & 15, m = b & 7;
    float v = e ? __uint_as_float(((unsigned)(e + 120) << 23) | ((unsigned)m << 20))
                : (float)m * 0.001953125f;
    return s ? -v : v;
#endif
}

__device__ __forceinline__ float wave_sum64(float v) {
#pragma unroll
    for (int o = 32; o > 0; o >>= 1) v += __shfl_xor(v, o);
    return v;
}
__device__ __forceinline__ float sum16(float v) {
#pragma unroll
    for (int o = 8; o > 0; o >>= 1) v += __shfl_xor(v, o);
    return v;
}

// ---------------- weight prep ----------------
__global__ __launch_bounds__(256) void k_wprep(const float* __restrict__ in_w,
                                               const float* __restrict__ w1,
                                               const float* __restrict__ w2,
                                               unsigned short* __restrict__ fin,
                                               unsigned short* __restrict__ f1,
                                               unsigned short* __restrict__ f2) {
    int t = blockIdx.x * 256 + threadIdx.x;
    if (t < 12288) {  // in_w: [176->192 pad][64]
        int e = t;
        int r = e & 7, lane = (e >> 3) & 63, j = (e >> 9) & 3, s = e >> 11;
        int k = s * 32 + ((lane >> 4) << 3) + r;
        int n = (j << 4) + (lane & 15);
        fin[e] = (k < NODE_FEAT) ? f2bf(in_w[k * 64 + n]) : (unsigned short)0;
    } else if (t < 12288 + 32768) {  // w1: 4 layers x [64][128]
        int e = t - 12288;
        int L = e >> 13, e2 = e & 8191;
        int r = e2 & 7, lane = (e2 >> 3) & 63, j = (e2 >> 9) & 7, s = (e2 >> 12) & 1;
        int k = s * 32 + ((lane >> 4) << 3) + r;
        int n = (j << 4) + (lane & 15);
        f1[e] = f2bf(w1[L * 8192 + k * 128 + n]);
    } else if (t < 12288 + 32768 + 32768) {  // w2: 4 layers x [128][64]
        int e = t - 45056;
        int L = e >> 13, e2 = e & 8191;
        int r = e2 & 7, lane = (e2 >> 3) & 63, j = (e2 >> 9) & 3, s = (e2 >> 11) & 3;
        int k = s * 32 + ((lane >> 4) << 3) + r;
        int n = (j << 4) + (lane & 15);
        f2[e] = f2bf(w2[L * 8192 + k * 64 + n]);
    }
}

// ---------------- input projection via MFMA -> bf16 + fp8 h ----------------
__global__ __launch_bounds__(256) void k_inproj_mfma(const float* __restrict__ x,
                                                     const unsigned short* __restrict__ wfrag,
                                                     const float* __restrict__ in_b,
                                                     unsigned short* __restrict__ hb,
                                                     unsigned char* __restrict__ hf8) {
    __shared__ unsigned short lw[12288];  // 24 KB
    const int tid = threadIdx.x;
    {
        const bf16x8* src = (const bf16x8*)wfrag;
        bf16x8* dst = (bf16x8*)lw;
        for (int i = tid; i < 1536; i += 256) dst[i] = src[i];
    }
    __syncthreads();
    const int wv = tid >> 6, lane = tid & 63;
    const int lrow = lane & 15, lgrp = lane >> 4;
    float ib[4];
#pragma unroll
    for (int j = 0; j < 4; ++j) ib[j] = in_b[16 * j + lrow];
    const int nwaves = gridDim.x * 4;
    for (int tile = blockIdx.x * 4 + wv; tile < 3125; tile += nwaves) {
        const int m0 = tile * 16;
        f32x4 acc[4];
#pragma unroll
        for (int j = 0; j < 4; ++j) acc[j] = (f32x4){ib[j], ib[j], ib[j], ib[j]};
#pragma unroll
        for (int s = 0; s < 6; ++s) {
            const int kbase = s * 32 + lgrp * 8;
            bf16x8 a;
            if (kbase < NODE_FEAT) {
                const float* p = x + (size_t)(m0 + lrow) * NODE_FEAT + kbase;
                float4 fa = *(const float4*)p;
                float4 fb = *(const float4*)(p + 4);
                a[0] = (short)f2bf(fa.x); a[1] = (short)f2bf(fa.y);
                a[2] = (short)f2bf(fa.z); a[3] = (short)f2bf(fa.w);
                a[4] = (short)f2bf(fb.x); a[5] = (short)f2bf(fb.y);
                a[6] = (short)f2bf(fb.z); a[7] = (short)f2bf(fb.w);
            } else {
                a = (bf16x8){0, 0, 0, 0, 0, 0, 0, 0};
            }
#pragma unroll
            for (int j = 0; j < 4; ++j) {
                bf16x8 b = *(const bf16x8*)&lw[((s * 4 + j) * 64 + lane) * 8];
                acc[j] = __builtin_amdgcn_mfma_f32_16x16x32_bf16(a, b, acc[j], 0, 0, 0);
            }
        }
#pragma unroll
        for (int j = 0; j < 4; ++j) {
            const int col = 16 * j + lrow;
#pragma unroll
            for (int r = 0; r < 4; ++r) {
                const int node = m0 + lgrp * 4 + r;
                float v = acc[j][r];
                __builtin_nontemporal_store(f2bf(v), &hb[(size_t)node * 64 + col]);
                hf8[(size_t)node * 64 + col] = f2fp8(v);  // cached: gather table
            }
        }
    }
}

// ---------------- CSR build (padded counters: 1 per 64B line) ----------------
__global__ __launch_bounds__(256) void k_hist(const int* __restrict__ ei,
                                              int* __restrict__ cnt,   // stride 16
                                              int* __restrict__ erank) {
    int e = blockIdx.x * 256 + threadIdx.x;
    if (e < N_EDGES) erank[e] = atomicAdd(&cnt[ei[N_EDGES + e] << 4], 1);
}

__global__ __launch_bounds__(256) void k_scan_part(const int* __restrict__ cnt,  // stride 16
                                                   int* __restrict__ blksum) {
    const int b = blockIdx.x, t = threadIdx.x;
    const int base = b * 1024 + t * 4;
    int s = 0;
#pragma unroll
    for (int i = 0; i < 4; ++i) {
        int idx = base + i;
        if (idx < N_NODES) s += cnt[idx << 4];
    }
#pragma unroll
    for (int o = 32; o > 0; o >>= 1) s += __shfl_xor(s, o);
    __shared__ int wt[4];
    if ((t & 63) == 0) wt[t >> 6] = s;
    __syncthreads();
    if (t == 0) blksum[b] = wt[0] + wt[1] + wt[2] + wt[3];
}

// scan_add with folded top-level scan
__global__ __launch_bounds__(256) void k_scan_add(const int* __restrict__ cnt,  // stride 16
                                                  const int* __restrict__ blksum,
                                                  int* __restrict__ row_ptr) {
    const int b = blockIdx.x, t = threadIdx.x;
    __shared__ int boff_s;
    if (t < 64) {
        int v = (t < SCAN_NB) ? blksum[t] : 0;
        int incl = v;
#pragma unroll
        for (int o = 1; o < 64; o <<= 1) {
            int u = __shfl_up(incl, o);
            if (t >= o) incl += u;
        }
        if (t == b) boff_s = incl - v;
        if (b == 0 && t == 63) row_ptr[N_NODES] = incl;
    }
    __syncthreads();
    const int base = b * 1024 + t * 4;
    int c[4];
    int tsum = 0;
#pragma unroll
    for (int i = 0; i < 4; ++i) {
        int idx = base + i;
        c[i] = (idx < N_NODES) ? cnt[idx << 4] : 0;
        tsum += c[i];
    }
    int incl = tsum;
#pragma unroll
    for (int o = 1; o < 64; o <<= 1) {
        int u = __shfl_up(incl, o);
        if ((t & 63) >= o) incl += u;
    }
    __shared__ int wt[4];
    const int wv = t >> 6;
    if ((t & 63) == 63) wt[wv] = incl;
    __syncthreads();
    int run = boff_s + (incl - tsum);
    for (int w = 0; w < wv; ++w) run += wt[w];
#pragma unroll
    for (int i = 0; i < 4; ++i) {
        int idx = base + i;
        if (idx < N_NODES) row_ptr[idx] = run;
        run += c[i];
    }
}

__global__ __launch_bounds__(256) void k_scatter(const int* __restrict__ ei,
                                                 const float4* __restrict__ ea,
                                                 const int* __restrict__ row_ptr,
                                                 const int* __restrict__ erank,
                                                 int4* __restrict__ rec) {
    int e = blockIdx.x * 256 + threadIdx.x;
    if (e >= N_EDGES) return;
    int d = ei[N_EDGES + e];
    float4 a = ea[e];
    int4 r;
    r.x = pack2(a.x, a.y);
    r.y = pack2(a.z, a.w);
    r.z = ei[e];
    r.w = 0;
    rec[row_ptr[d] + erank[e]] = r;
}

// ---------------- gather + aggregate (fp8 L2-resident gathers) ----------------
__global__ __launch_bounds__(256) void k_aggr(const unsigned short* __restrict__ hb_in,
                                              const unsigned char* __restrict__ hf8_in,
                                              unsigned short* __restrict__ zb,
                                              const int* __restrict__ row_ptr,
                                              const int4* __restrict__ rec,
                                              const float* __restrict__ ew,
                                              const float* __restrict__ eb) {
    const int wv = threadIdx.x >> 6, lane = threadIdx.x & 63;
    const int node = blockIdx.x * 4 + wv;  // 12500*4 = 50000 exact
    const float ew0 = ew[0 * 64 + lane], ew1 = ew[1 * 64 + lane];
    const float ew2 = ew[2 * 64 + lane], ew3 = ew[3 * 64 + lane];
    const float ebl = eb[lane];
    const int beg = __builtin_amdgcn_readfirstlane(row_ptr[node]);
    const int end = __builtin_amdgcn_readfirstlane(row_ptr[node + 1]);
    float acc = bf2f(__builtin_nontemporal_load(&hb_in[(size_t)node * 64 + lane]));
    int i = beg;
    for (; i + 8 <= end; i += 8) {
        int d0[8], d1[8], sx[8];
#pragma unroll
        for (int t = 0; t < 8; ++t) {
            ll2 r = __builtin_nontemporal_load((const ll2*)(rec + i + t));
            d0[t] = __builtin_amdgcn_readfirstlane((int)(r[0] & 0xffffffffLL));
            d1[t] = __builtin_amdgcn_readfirstlane((int)(r[0] >> 32));
            sx[t] = __builtin_amdgcn_readfirstlane((int)(r[1] & 0xffffffffLL));
        }
        float gg[8];
#pragma unroll
        for (int t = 0; t < 8; ++t)
            gg[t] = fp82f(hf8_in[((size_t)sx[t] << 6) + lane]);
#pragma unroll
        for (int t = 0; t < 8; ++t) {
            float a0 = __uint_as_float((unsigned)d0[t] << 16);
            float a1 = __uint_as_float((unsigned)d0[t] & 0xffff0000u);
            float a2 = __uint_as_float((unsigned)d1[t] << 16);
            float a3 = __uint_as_float((unsigned)d1[t] & 0xffff0000u);
            float v = fmaf(a0, ew0, fmaf(a1, ew1, fmaf(a2, ew2, fmaf(a3, ew3, ebl))));
            acc += fmaxf(v + gg[t], 0.0f);
        }
    }
    if (i < end) {  // masked tail (1..7), clamped loads -> same-line broadcasts
        const int n = end - i;
        int d0[8], d1[8], sx[8];
#pragma unroll
        for (int t = 0; t < 8; ++t) {
            int idx = i + ((t < n) ? t : (n - 1));
            ll2 r = __builtin_nontemporal_load((const ll2*)(rec + idx));
            d0[t] = __builtin_amdgcn_readfirstlane((int)(r[0] & 0xffffffffLL));
            d1[t] = __builtin_amdgcn_readfirstlane((int)(r[0] >> 32));
            sx[t] = __builtin_amdgcn_readfirstlane((int)(r[1] & 0xffffffffLL));
        }
        float gg[8];
#pragma unroll
        for (int t = 0; t < 8; ++t)
            gg[t] = fp82f(hf8_in[((size_t)sx[t] << 6) + lane]);
#pragma unroll
        for (int t = 0; t < 8; ++t) {
            float m = (t < n) ? 1.0f : 0.0f;
            float a0 = __uint_as_float((unsigned)d0[t] << 16);
            float a1 = __uint_as_float((unsigned)d0[t] & 0xffff0000u);
            float a2 = __uint_as_float((unsigned)d1[t] << 16);
            float a3 = __uint_as_float((unsigned)d1[t] & 0xffff0000u);
            float v = fmaf(a0, ew0, fmaf(a1, ew1, fmaf(a2, ew2, fmaf(a3, ew3, ebl))));
            acc += m * fmaxf(v + gg[t], 0.0f);
        }
    }
    __builtin_nontemporal_store(f2bf(acc), &zb[(size_t)node * 64 + lane]);
}

// ---------------- MLP + LN + relu via MFMA ----------------
__global__ __launch_bounds__(256) void k_mlp_mfma(const unsigned short* __restrict__ zb,
                                                  unsigned short* __restrict__ hb_out,
                                                  unsigned char* __restrict__ hf8_out,
                                                  const unsigned short* __restrict__ f1,
                                                  const unsigned short* __restrict__ f2,
                                                  const float* __restrict__ b1,
                                                  const float* __restrict__ b2,
                                                  const float* __restrict__ lng,
                                                  const float* __restrict__ lnb) {
    __shared__ unsigned short w1f[8192];
    __shared__ unsigned short w2f[8192];
    __shared__ unsigned short z1s[4][2048];
    const int tid = threadIdx.x;
    {
        const bf16x8* s1 = (const bf16x8*)f1;
        const bf16x8* s2 = (const bf16x8*)f2;
        bf16x8* d1 = (bf16x8*)w1f;
        bf16x8* d2 = (bf16x8*)w2f;
        for (int i = tid; i < 1024; i += 256) { d1[i] = s1[i]; d2[i] = s2[i]; }
    }
    __syncthreads();
    const int wv = tid >> 6, lane = tid & 63;
    const int lrow = lane & 15, lgrp = lane >> 4;
    unsigned short* zs = z1s[wv];
    float bb1[8], bb2[4], g4[4], be4[4];
#pragma unroll
    for (int j = 0; j < 8; ++j) bb1[j] = b1[16 * j + lrow];
#pragma unroll
    for (int j = 0; j < 4; ++j) {
        bb2[j] = b2[16 * j + lrow];
        g4[j] = lng[16 * j + lrow];
        be4[j] = lnb[16 * j + lrow];
    }
    const int nwaves = gridDim.x * 4;
    for (int tile = blockIdx.x * 4 + wv; tile < 3125; tile += nwaves) {
        const int m0 = tile * 16;
        f32x4 acc1[8];
#pragma unroll
        for (int j = 0; j < 8; ++j) acc1[j] = (f32x4){bb1[j], bb1[j], bb1[j], bb1[j]};
#pragma unroll
        for (int s = 0; s < 2; ++s) {
            const int kbase = s * 32 + lgrp * 8;
            bf16x8 a = *(const bf16x8*)&zb[(size_t)(m0 + lrow) * 64 + kbase];
#pragma unroll
            for (int j = 0; j < 8; ++j) {
                bf16x8 b = *(const bf16x8*)&w1f[((s * 8 + j) * 64 + lane) * 8];
                acc1[j] = __builtin_amdgcn_mfma_f32_16x16x32_bf16(a, b, acc1[j], 0, 0, 0);
            }
        }
#pragma unroll
        for (int j = 0; j < 8; ++j) {
            const int col = 16 * j + lrow;
#pragma unroll
            for (int r = 0; r < 4; ++r) {
                const int row = lgrp * 4 + r;
                const int idx = (row * 128 + col) ^ ((row & 7) << 3);
                zs[idx] = f2bf(fmaxf(acc1[j][r], 0.0f));
            }
        }
        f32x4 acc2[4];
#pragma unroll
        for (int j = 0; j < 4; ++j) acc2[j] = (f32x4){bb2[j], bb2[j], bb2[j], bb2[j]};
#pragma unroll
        for (int s = 0; s < 4; ++s) {
            const int kbase = s * 32 + lgrp * 8;
            const int idx = (lrow * 128 + kbase) ^ ((lrow & 7) << 3);
            bf16x8 a = *(const bf16x8*)&zs[idx];
#pragma unroll
            for (int j = 0; j < 4; ++j) {
                bf16x8 b = *(const bf16x8*)&w2f[((s * 4 + j) * 64 + lane) * 8];
                acc2[j] = __builtin_amdgcn_mfma_f32_16x16x32_bf16(a, b, acc2[j], 0, 0, 0);
            }
        }
#pragma unroll
        for (int r = 0; r < 4; ++r) {
            float sum = acc2[0][r] + acc2[1][r] + acc2[2][r] + acc2[3][r];
            sum = sum16(sum);
            const float mu = sum * (1.0f / 64.0f);
            float sq = 0.0f;
#pragma unroll
            for (int j = 0; j < 4; ++j) {
                float d = acc2[j][r] - mu;
                sq = fmaf(d, d, sq);
            }
            sq = sum16(sq);
            const float rstd = rsqrtf(sq * (1.0f / 64.0f) + LN_EPS);
            const int node = m0 + lgrp * 4 + r;
#pragma unroll
            for (int j = 0; j < 4; ++j) {
                const int col = 16 * j + lrow;
                float d = acc2[j][r] - mu;
                float hn = fmaxf(fmaf(g4[j] * d, rstd, be4[j]), 0.0f);
                __builtin_nontemporal_store(f2bf(hn), &hb_out[(size_t)node * 64 + col]);
                hf8_out[(size_t)node * 64 + col] = f2fp8(hn);
            }
        }
    }
}

// ---------------- pool (partials, no atomics) + regressor ----------------
__global__ __launch_bounds__(256) void k_pool(const unsigned short* __restrict__ hb,
                                              float* __restrict__ gpart) {
    __shared__ float red[256];
    const int tid = threadIdx.x;
    const int lane = tid & 63;
    float part = 0.0f;
    for (int i = blockIdx.x * 4 + (tid >> 6); i < N_NODES; i += gridDim.x * 4)
        part += bf2f(hb[(size_t)i * 64 + lane]);
    red[tid] = part;
    __syncthreads();
    if (tid < 64) {
        gpart[blockIdx.x * 64 + tid] = red[tid] + red[tid + 64] + red[tid + 128] + red[tid + 192];
    }
}

__global__ __launch_bounds__(64) void k_reg(const float* __restrict__ gpart,
                                            const float* __restrict__ w1,
                                            const float* __restrict__ b1,
                                            const float* __restrict__ w2,
                                            const float* __restrict__ b2,
                                            float* __restrict__ out) {
    const int j = threadIdx.x;
    float gj = 0.0f;
    for (int b = 0; b < 256; ++b) gj += gpart[b * 64 + j];
    __shared__ float gs[64];
    gs[j] = gj;
    __syncthreads();
    const int jm = j & 31;
    float acc = b1[jm];
#pragma unroll 8
    for (int k = 0; k < 64; ++k) {
        float gk = gs[k];
        acc = fmaf(gk, w1[k * 32 + jm], acc);
    }
    float contrib = (j < 32) ? fmaxf(acc, 0.0f) * w2[jm] : 0.0f;
    float s = wave_sum64(contrib);
    if (j == 0) out[0] = s + b2[0];
}

extern "C" void kernel_launch(void* const* d_in, const int* in_sizes, int n_in,
                              void* d_out, int out_size, void* d_ws, size_t ws_size,
                              hipStream_t stream) {
    const float* x      = (const float*)d_in[0];
    const int*   ei     = (const int*)d_in[1];
    const float* ea     = (const float*)d_in[2];
    const float* in_w   = (const float*)d_in[3];
    const float* in_b   = (const float*)d_in[4];
    const float* edge_w = (const float*)d_in[5];
    const float* edge_b = (const float*)d_in[6];
    const float* mlp_w1 = (const float*)d_in[7];
    const float* mlp_b1 = (const float*)d_in[8];
    const float* mlp_w2 = (const float*)d_in[9];
    const float* mlp_b2 = (const float*)d_in[10];
    const float* ln_g   = (const float*)d_in[11];
    const float* ln_b   = (const float*)d_in[12];
    const float* reg_w1 = (const float*)d_in[13];
    const float* reg_b1 = (const float*)d_in[14];
    const float* reg_w2 = (const float*)d_in[15];
    const float* reg_b2 = (const float*)d_in[16];

    char* ws = (char*)d_ws;
    unsigned short* hb0     = (unsigned short*)ws; ws += (size_t)N_NODES * 64 * 2;
    unsigned short* hb1     = (unsigned short*)ws; ws += (size_t)N_NODES * 64 * 2;
    unsigned short* zb      = (unsigned short*)ws; ws += (size_t)N_NODES * 64 * 2;
    unsigned char*  hf8_0   = (unsigned char*)ws;  ws += (size_t)N_NODES * 64;
    unsigned char*  hf8_1   = (unsigned char*)ws;  ws += (size_t)N_NODES * 64;
    int4*           rec     = (int4*)ws;           ws += (size_t)N_EDGES * 16;
    unsigned short* fin     = (unsigned short*)ws; ws += 12288 * 2;
    unsigned short* f1      = (unsigned short*)ws; ws += 32768 * 2;
    unsigned short* f2      = (unsigned short*)ws; ws += 32768 * 2;
    int*            erank   = (int*)ws;            ws += (size_t)N_EDGES * 4;
    int*            row_ptr = (int*)ws;            ws += (size_t)(N_NODES + 1) * 4;
    int*            cnt     = (int*)ws;            ws += (size_t)N_NODES * 16 * 4;  // padded: 1 counter / 64B
    int*            blksum  = (int*)ws;            ws += SCAN_NB * 4;
    float*          gpart   = (float*)ws;          ws += 256 * 64 * 4;
    float*          outf    = (float*)d_out;

    const int eb_blocks = (N_EDGES + 255) / 256;

    k_wprep<<<304, 256, 0, stream>>>(in_w, mlp_w1, mlp_w2, fin, f1, f2);

    (void)hipMemsetAsync(cnt, 0, (size_t)N_NODES * 16 * 4, stream);
    k_hist<<<eb_blocks, 256, 0, stream>>>(ei, cnt, erank);
    k_scan_part<<<SCAN_NB, 256, 0, stream>>>(cnt, blksum);
    k_scan_add<<<SCAN_NB, 256, 0, stream>>>(cnt, blksum, row_ptr);
    k_scatter<<<eb_blocks, 256, 0, stream>>>(ei, (const float4*)ea, row_ptr, erank, rec);

    k_inproj_mfma<<<512, 256, 0, stream>>>(x, fin, in_b, hb0, hf8_0);

    unsigned short* hbA = hb0;
    unsigned short* hbB = hb1;
    unsigned char*  hfA = hf8_0;
    unsigned char*  hfB = hf8_1;
    for (int l = 0; l < 4; ++l) {
        k_aggr<<<N_NODES / 4, 256, 0, stream>>>(hbA, hfA, zb, row_ptr, rec,
                                                edge_w + l * 4 * 64,
                                                edge_b + l * 64);
        k_mlp_mfma<<<768, 256, 0, stream>>>(zb, hbB, hfB,
                                            f1 + l * 8192, f2 + l * 8192,
                                            mlp_b1 + l * 128, mlp_b2 + l * 64,
                                            ln_g + l * 64, ln_b + l * 64);
        unsigned short* tb = hbA; hbA = hbB; hbB = tb;
        unsigned char*  tf = hfA; hfA = hfB; hfB = tf;
    }

    k_pool<<<256, 256, 0, stream>>>(hbA, gpart);
    k_reg<<<1, 64, 0, stream>>>(gpart, reg_w1, reg_b1, reg_w2, reg_b2, outf);
}

// Round 15
// 271.472 us; speedup vs baseline: 1.7511x; 1.0198x over previous
//
#include <hip/hip_runtime.h>

#define N_NODES 50000
#define N_EDGES 800000
#define NODE_FEAT 176
#define HIDDEN 64
#define LN_EPS 1e-5f
#define SCAN_NB 49  // ceil(50000/1024)

typedef short bf16x8 __attribute__((ext_vector_type(8)));
typedef float f32x4 __attribute__((ext_vector_type(4)));
typedef long long ll2 __attribute__((ext_vector_type(2)));

__device__ __forceinline__ unsigned short f2bf(float f) {
    unsigned int u = __float_as_uint(f);
    u += 0x7FFFu + ((u >> 16) & 1u);  // round-to-nearest-even
    return (unsigned short)(u >> 16);
}
__device__ __forceinline__ int pack2(float lo, float hi) {
    return (int)(((unsigned)f2bf(hi) << 16) | (unsigned)f2bf(lo));
}
__device__ __forceinline__ float bf2f(unsigned short s) {
    return __uint_as_float(((unsigned int)s) << 16);
}

#if __has_builtin(__builtin_amdgcn_cvt_pk_fp8_f32) && __has_builtin(__builtin_amdgcn_cvt_f32_fp8)
#define HW_FP8 1
#endif

__device__ __forceinline__ unsigned char f2fp8(float f) {
#ifdef HW_FP8
    return (unsigned char)(__builtin_amdgcn_cvt_pk_fp8_f32(f, f, 0, false) & 0xff);
#else
    unsigned u = __float_as_uint(f);
    unsigned s = (u >> 24) & 0x80u;
    float a = fabsf(f);
    if (a >= 448.f) return (unsigned char)(s | 0x7E);
    if (a < 0.0078125f) {
        int m = (int)fmaf(a, 512.0f, 0.5f);
        return (unsigned char)(s | (m > 7 ? 7 : m));
    }
    unsigned au = u & 0x7fffffffu;
    au += 0x7ffffu + ((au >> 20) & 1u);
    int e8 = (int)(au >> 23) - 120;
    if (e8 <= 0) {
        int m = (int)fmaf(__uint_as_float(au), 512.0f, 0.5f);
        return (unsigned char)(s | (m > 7 ? 7 : m));
    }
    if (e8 > 15) return (unsigned char)(s | 0x7E);
    return (unsigned char)(s | (e8 << 3) | ((au >> 20) & 7));
#endif
}
__device__ __forceinline__ float fp82f(int b) {
#ifdef HW_FP8
    return __builtin_amdgcn_cvt_f32_fp8(b & 0xff, 0);
#else
    int s = (b >> 7) & 1, e = (b >> 3) & 15, m = b & 7;
    float v = e ? __uint_as_float(((unsigned)(e + 120) << 23) | ((unsigned)m << 20))
                : (float)m * 0.001953125f;
    return s ? -v : v;
#endif
}

__device__ __forceinline__ float wave_sum64(float v) {
#pragma unroll
    for (int o = 32; o > 0; o >>= 1) v += __shfl_xor(v, o);
    return v;
}
__device__ __forceinline__ float sum16(float v) {
#pragma unroll
    for (int o = 8; o > 0; o >>= 1) v += __shfl_xor(v, o);
    return v;
}

// ---------------- weight prep (+ padded-cnt zeroing) ----------------
__global__ __launch_bounds__(256) void k_wprep(const float* __restrict__ in_w,
                                               const float* __restrict__ w1,
                                               const float* __restrict__ w2,
                                               unsigned short* __restrict__ fin,
                                               unsigned short* __restrict__ f1,
                                               unsigned short* __restrict__ f2,
                                               int* __restrict__ cnt) {
    int t = blockIdx.x * 256 + threadIdx.x;
    if (t < N_NODES) {  // zero one 64B counter line
        int4 z = {0, 0, 0, 0};
        int4* p = (int4*)(cnt + ((size_t)t << 4));
        p[0] = z; p[1] = z; p[2] = z; p[3] = z;
    }
    if (t < 12288) {  // in_w: [176->192 pad][64]
        int e = t;
        int r = e & 7, lane = (e >> 3) & 63, j = (e >> 9) & 3, s = e >> 11;
        int k = s * 32 + ((lane >> 4) << 3) + r;
        int n = (j << 4) + (lane & 15);
        fin[e] = (k < NODE_FEAT) ? f2bf(in_w[k * 64 + n]) : (unsigned short)0;
    } else if (t < 12288 + 32768) {  // w1: 4 layers x [64][128]
        int e = t - 12288;
        int L = e >> 13, e2 = e & 8191;
        int r = e2 & 7, lane = (e2 >> 3) & 63, j = (e2 >> 9) & 7, s = (e2 >> 12) & 1;
        int k = s * 32 + ((lane >> 4) << 3) + r;
        int n = (j << 4) + (lane & 15);
        f1[e] = f2bf(w1[L * 8192 + k * 128 + n]);
    } else if (t < 12288 + 32768 + 32768) {  // w2: 4 layers x [128][64]
        int e = t - 45056;
        int L = e >> 13, e2 = e & 8191;
        int r = e2 & 7, lane = (e2 >> 3) & 63, j = (e2 >> 9) & 3, s = (e2 >> 11) & 3;
        int k = s * 32 + ((lane >> 4) << 3) + r;
        int n = (j << 4) + (lane & 15);
        f2[e] = f2bf(w2[L * 8192 + k * 64 + n]);
    }
}

// ---------------- input projection via MFMA -> bf16 + fp8 h ----------------
__global__ __launch_bounds__(256) void k_inproj_mfma(const float* __restrict__ x,
                                                     const unsigned short* __restrict__ wfrag,
                                                     const float* __restrict__ in_b,
                                                     unsigned short* __restrict__ hb,
                                                     unsigned char* __restrict__ hf8) {
    __shared__ unsigned short lw[12288];  // 24 KB
    const int tid = threadIdx.x;
    {
        const bf16x8* src = (const bf16x8*)wfrag;
        bf16x8* dst = (bf16x8*)lw;
        for (int i = tid; i < 1536; i += 256) dst[i] = src[i];
    }
    __syncthreads();
    const int wv = tid >> 6, lane = tid & 63;
    const int lrow = lane & 15, lgrp = lane >> 4;
    float ib[4];
#pragma unroll
    for (int j = 0; j < 4; ++j) ib[j] = in_b[16 * j + lrow];
    const int nwaves = gridDim.x * 4;
    for (int tile = blockIdx.x * 4 + wv; tile < 3125; tile += nwaves) {
        const int m0 = tile * 16;
        f32x4 acc[4];
#pragma unroll
        for (int j = 0; j < 4; ++j) acc[j] = (f32x4){ib[j], ib[j], ib[j], ib[j]};
#pragma unroll
        for (int s = 0; s < 6; ++s) {
            const int kbase = s * 32 + lgrp * 8;
            bf16x8 a;
            if (kbase < NODE_FEAT) {
                const float* p = x + (size_t)(m0 + lrow) * NODE_FEAT + kbase;
                float4 fa = *(const float4*)p;
                float4 fb = *(const float4*)(p + 4);
                a[0] = (short)f2bf(fa.x); a[1] = (short)f2bf(fa.y);
                a[2] = (short)f2bf(fa.z); a[3] = (short)f2bf(fa.w);
                a[4] = (short)f2bf(fb.x); a[5] = (short)f2bf(fb.y);
                a[6] = (short)f2bf(fb.z); a[7] = (short)f2bf(fb.w);
            } else {
                a = (bf16x8){0, 0, 0, 0, 0, 0, 0, 0};
            }
#pragma unroll
            for (int j = 0; j < 4; ++j) {
                bf16x8 b = *(const bf16x8*)&lw[((s * 4 + j) * 64 + lane) * 8];
                acc[j] = __builtin_amdgcn_mfma_f32_16x16x32_bf16(a, b, acc[j], 0, 0, 0);
            }
        }
#pragma unroll
        for (int j = 0; j < 4; ++j) {
            const int col = 16 * j + lrow;
#pragma unroll
            for (int r = 0; r < 4; ++r) {
                const int node = m0 + lgrp * 4 + r;
                float v = acc[j][r];
                __builtin_nontemporal_store(f2bf(v), &hb[(size_t)node * 64 + col]);
                hf8[(size_t)node * 64 + col] = f2fp8(v);  // cached: gather table
            }
        }
    }
}

// ---------------- CSR build (padded counters: 1 per 64B line) ----------------
__global__ __launch_bounds__(256) void k_hist(const int* __restrict__ ei,
                                              int* __restrict__ cnt,   // stride 16
                                              int* __restrict__ erank) {
    int e = blockIdx.x * 256 + threadIdx.x;
    if (e < N_EDGES) erank[e] = atomicAdd(&cnt[ei[N_EDGES + e] << 4], 1);
}

__global__ __launch_bounds__(256) void k_scan_part(const int* __restrict__ cnt,  // stride 16
                                                   int* __restrict__ blksum) {
    const int b = blockIdx.x, t = threadIdx.x;
    const int base = b * 1024 + t * 4;
    int s = 0;
#pragma unroll
    for (int i = 0; i < 4; ++i) {
        int idx = base + i;
        if (idx < N_NODES) s += cnt[idx << 4];
    }
#pragma unroll
    for (int o = 32; o > 0; o >>= 1) s += __shfl_xor(s, o);
    __shared__ int wt[4];
    if ((t & 63) == 0) wt[t >> 6] = s;
    __syncthreads();
    if (t == 0) blksum[b] = wt[0] + wt[1] + wt[2] + wt[3];
}

// scan_add with folded top-level scan
__global__ __launch_bounds__(256) void k_scan_add(const int* __restrict__ cnt,  // stride 16
                                                  const int* __restrict__ blksum,
                                                  int* __restrict__ row_ptr) {
    const int b = blockIdx.x, t = threadIdx.x;
    __shared__ int boff_s;
    if (t < 64) {
        int v = (t < SCAN_NB) ? blksum[t] : 0;
        int incl = v;
#pragma unroll
        for (int o = 1; o < 64; o <<= 1) {
            int u = __shfl_up(incl, o);
            if (t >= o) incl += u;
        }
        if (t == b) boff_s = incl - v;
        if (b == 0 && t == 63) row_ptr[N_NODES] = incl;
    }
    __syncthreads();
    const int base = b * 1024 + t * 4;
    int c[4];
    int tsum = 0;
#pragma unroll
    for (int i = 0; i < 4; ++i) {
        int idx = base + i;
        c[i] = (idx < N_NODES) ? cnt[idx << 4] : 0;
        tsum += c[i];
    }
    int incl = tsum;
#pragma unroll
    for (int o = 1; o < 64; o <<= 1) {
        int u = __shfl_up(incl, o);
        if ((t & 63) >= o) incl += u;
    }
    __shared__ int wt[4];
    const int wv = t >> 6;
    if ((t & 63) == 63) wt[wv] = incl;
    __syncthreads();
    int run = boff_s + (incl - tsum);
    for (int w = 0; w < wv; ++w) run += wt[w];
#pragma unroll
    for (int i = 0; i < 4; ++i) {
        int idx = base + i;
        if (idx < N_NODES) row_ptr[idx] = run;
        run += c[i];
    }
}

__global__ __launch_bounds__(256) void k_scatter(const int* __restrict__ ei,
                                                 const float4* __restrict__ ea,
                                                 const int* __restrict__ row_ptr,
                                                 const int* __restrict__ erank,
                                                 int4* __restrict__ rec) {
    int e = blockIdx.x * 256 + threadIdx.x;
    if (e >= N_EDGES) return;
    int d = ei[N_EDGES + e];
    float4 a = ea[e];
    int4 r;
    r.x = pack2(a.x, a.y);
    r.y = pack2(a.z, a.w);
    r.z = ei[e];
    r.w = 0;
    rec[row_ptr[d] + erank[e]] = r;
}

// ---------------- gather + aggregate (fp8 L2-resident gathers) ----------------
__global__ __launch_bounds__(256) void k_aggr(const unsigned short* __restrict__ hb_in,
                                              const unsigned char* __restrict__ hf8_in,
                                              unsigned short* __restrict__ zb,
                                              const int* __restrict__ row_ptr,
                                              const int4* __restrict__ rec,
                                              const float* __restrict__ ew,
                                              const float* __restrict__ eb) {
    const int wv = threadIdx.x >> 6, lane = threadIdx.x & 63;
    const int node = blockIdx.x * 4 + wv;  // 12500*4 = 50000 exact
    const float ew0 = ew[0 * 64 + lane], ew1 = ew[1 * 64 + lane];
    const float ew2 = ew[2 * 64 + lane], ew3 = ew[3 * 64 + lane];
    const float ebl = eb[lane];
    const int beg = __builtin_amdgcn_readfirstlane(row_ptr[node]);
    const int end = __builtin_amdgcn_readfirstlane(row_ptr[node + 1]);
    float acc = bf2f(__builtin_nontemporal_load(&hb_in[(size_t)node * 64 + lane]));
    int i = beg;
    for (; i + 8 <= end; i += 8) {
        int d0[8], d1[8], sx[8];
#pragma unroll
        for (int t = 0; t < 8; ++t) {
            ll2 r = __builtin_nontemporal_load((const ll2*)(rec + i + t));
            d0[t] = __builtin_amdgcn_readfirstlane((int)(r[0] & 0xffffffffLL));
            d1[t] = __builtin_amdgcn_readfirstlane((int)(r[0] >> 32));
            sx[t] = __builtin_amdgcn_readfirstlane((int)(r[1] & 0xffffffffLL));
        }
        float gg[8];
#pragma unroll
        for (int t = 0; t < 8; ++t)
            gg[t] = fp82f(hf8_in[((size_t)sx[t] << 6) + lane]);
#pragma unroll
        for (int t = 0; t < 8; ++t) {
            float a0 = __uint_as_float((unsigned)d0[t] << 16);
            float a1 = __uint_as_float((unsigned)d0[t] & 0xffff0000u);
            float a2 = __uint_as_float((unsigned)d1[t] << 16);
            float a3 = __uint_as_float((unsigned)d1[t] & 0xffff0000u);
            float v = fmaf(a0, ew0, fmaf(a1, ew1, fmaf(a2, ew2, fmaf(a3, ew3, ebl))));
            acc += fmaxf(v + gg[t], 0.0f);
        }
    }
    if (i < end) {  // masked tail (1..7), clamped loads -> same-line broadcasts
        const int n = end - i;
        int d0[8], d1[8], sx[8];
#pragma unroll
        for (int t = 0; t < 8; ++t) {
            int idx = i + ((t < n) ? t : (n - 1));
            ll2 r = __builtin_nontemporal_load((const ll2*)(rec + idx));
            d0[t] = __builtin_amdgcn_readfirstlane((int)(r[0] & 0xffffffffLL));
            d1[t] = __builtin_amdgcn_readfirstlane((int)(r[0] >> 32));
            sx[t] = __builtin_amdgcn_readfirstlane((int)(r[1] & 0xffffffffLL));
        }
        float gg[8];
#pragma unroll
        for (int t = 0; t < 8; ++t)
            gg[t] = fp82f(hf8_in[((size_t)sx[t] << 6) + lane]);
#pragma unroll
        for (int t = 0; t < 8; ++t) {
            float m = (t < n) ? 1.0f : 0.0f;
            float a0 = __uint_as_float((unsigned)d0[t] << 16);
            float a1 = __uint_as_float((unsigned)d0[t] & 0xffff0000u);
            float a2 = __uint_as_float((unsigned)d1[t] << 16);
            float a3 = __uint_as_float((unsigned)d1[t] & 0xffff0000u);
            float v = fmaf(a0, ew0, fmaf(a1, ew1, fmaf(a2, ew2, fmaf(a3, ew3, ebl))));
            acc += m * fmaxf(v + gg[t], 0.0f);
        }
    }
    __builtin_nontemporal_store(f2bf(acc), &zb[(size_t)node * 64 + lane]);
}

// ---------------- MLP + LN + relu via MFMA ----------------
__global__ __launch_bounds__(256) void k_mlp_mfma(const unsigned short* __restrict__ zb,
                                                  unsigned short* __restrict__ hb_out,
                                                  unsigned char* __restrict__ hf8_out,
                                                  const unsigned short* __restrict__ f1,
                                                  const unsigned short* __restrict__ f2,
                                                  const float* __restrict__ b1,
                                                  const float* __restrict__ b2,
                                                  const float* __restrict__ lng,
                                                  const float* __restrict__ lnb) {
    __shared__ unsigned short w1f[8192];
    __shared__ unsigned short w2f[8192];
    __shared__ unsigned short z1s[4][2048];
    const int tid = threadIdx.x;
    {
        const bf16x8* s1 = (const bf16x8*)f1;
        const bf16x8* s2 = (const bf16x8*)f2;
        bf16x8* d1 = (bf16x8*)w1f;
        bf16x8* d2 = (bf16x8*)w2f;
        for (int i = tid; i < 1024; i += 256) { d1[i] = s1[i]; d2[i] = s2[i]; }
    }
    __syncthreads();
    const int wv = tid >> 6, lane = tid & 63;
    const int lrow = lane & 15, lgrp = lane >> 4;
    unsigned short* zs = z1s[wv];
    float bb1[8], bb2[4], g4[4], be4[4];
#pragma unroll
    for (int j = 0; j < 8; ++j) bb1[j] = b1[16 * j + lrow];
#pragma unroll
    for (int j = 0; j < 4; ++j) {
        bb2[j] = b2[16 * j + lrow];
        g4[j] = lng[16 * j + lrow];
        be4[j] = lnb[16 * j + lrow];
    }
    const int nwaves = gridDim.x * 4;
    for (int tile = blockIdx.x * 4 + wv; tile < 3125; tile += nwaves) {
        const int m0 = tile * 16;
        f32x4 acc1[8];
#pragma unroll
    for (int j = 0; j < 8; ++j) acc1[j] = (f32x4){bb1[j], bb1[j], bb1[j], bb1[j]};
#pragma unroll
        for (int s = 0; s < 2; ++s) {
            const int kbase = s * 32 + lgrp * 8;
            bf16x8 a = *(const bf16x8*)&zb[(size_t)(m0 + lrow) * 64 + kbase];
#pragma unroll
            for (int j = 0; j < 8; ++j) {
                bf16x8 b = *(const bf16x8*)&w1f[((s * 8 + j) * 64 + lane) * 8];
                acc1[j] = __builtin_amdgcn_mfma_f32_16x16x32_bf16(a, b, acc1[j], 0, 0, 0);
            }
        }
#pragma unroll
        for (int j = 0; j < 8; ++j) {
            const int col = 16 * j + lrow;
#pragma unroll
            for (int r = 0; r < 4; ++r) {
                const int row = lgrp * 4 + r;
                const int idx = (row * 128 + col) ^ ((row & 7) << 3);
                zs[idx] = f2bf(fmaxf(acc1[j][r], 0.0f));
            }
        }
        f32x4 acc2[4];
#pragma unroll
        for (int j = 0; j < 4; ++j) acc2[j] = (f32x4){bb2[j], bb2[j], bb2[j], bb2[j]};
#pragma unroll
        for (int s = 0; s < 4; ++s) {
            const int kbase = s * 32 + lgrp * 8;
            const int idx = (lrow * 128 + kbase) ^ ((lrow & 7) << 3);
            bf16x8 a = *(const bf16x8*)&zs[idx];
#pragma unroll
            for (int j = 0; j < 4; ++j) {
                bf16x8 b = *(const bf16x8*)&w2f[((s * 4 + j) * 64 + lane) * 8];
                acc2[j] = __builtin_amdgcn_mfma_f32_16x16x32_bf16(a, b, acc2[j], 0, 0, 0);
            }
        }
#pragma unroll
        for (int r = 0; r < 4; ++r) {
            float sum = acc2[0][r] + acc2[1][r] + acc2[2][r] + acc2[3][r];
            sum = sum16(sum);
            const float mu = sum * (1.0f / 64.0f);
            float sq = 0.0f;
#pragma unroll
            for (int j = 0; j < 4; ++j) {
                float d = acc2[j][r] - mu;
                sq = fmaf(d, d, sq);
            }
            sq = sum16(sq);
            const float rstd = rsqrtf(sq * (1.0f / 64.0f) + LN_EPS);
            const int node = m0 + lgrp * 4 + r;
#pragma unroll
            for (int j = 0; j < 4; ++j) {
                const int col = 16 * j + lrow;
                float d = acc2[j][r] - mu;
                float hn = fmaxf(fmaf(g4[j] * d, rstd, be4[j]), 0.0f);
                __builtin_nontemporal_store(f2bf(hn), &hb_out[(size_t)node * 64 + col]);
                hf8_out[(size_t)node * 64 + col] = f2fp8(hn);
            }
        }
    }
}

// ---------------- pool (partials, no atomics) + regressor ----------------
__global__ __launch_bounds__(256) void k_pool(const unsigned short* __restrict__ hb,
                                              float* __restrict__ gpart) {
    __shared__ float red[256];
    const int tid = threadIdx.x;
    const int lane = tid & 63;
    float part = 0.0f;
    for (int i = blockIdx.x * 4 + (tid >> 6); i < N_NODES; i += gridDim.x * 4)
        part += bf2f(hb[(size_t)i * 64 + lane]);
    red[tid] = part;
    __syncthreads();
    if (tid < 64) {
        gpart[blockIdx.x * 64 + tid] = red[tid] + red[tid + 64] + red[tid + 128] + red[tid + 192];
    }
}

__global__ __launch_bounds__(64) void k_reg(const float* __restrict__ gpart,
                                            const float* __restrict__ w1,
                                            const float* __restrict__ b1,
                                            const float* __restrict__ w2,
                                            const float* __restrict__ b2,
                                            float* __restrict__ out) {
    const int j = threadIdx.x;
    float gj = 0.0f;
    for (int b = 0; b < 256; ++b) gj += gpart[b * 64 + j];
    __shared__ float gs[64];
    gs[j] = gj;
    __syncthreads();
    const int jm = j & 31;
    float acc = b1[jm];
#pragma unroll 8
    for (int k = 0; k < 64; ++k) {
        float gk = gs[k];
        acc = fmaf(gk, w1[k * 32 + jm], acc);
    }
    float contrib = (j < 32) ? fmaxf(acc, 0.0f) * w2[jm] : 0.0f;
    float s = wave_sum64(contrib);
    if (j == 0) out[0] = s + b2[0];
}

extern "C" void kernel_launch(void* const* d_in, const int* in_sizes, int n_in,
                              void* d_out, int out_size, void* d_ws, size_t ws_size,
                              hipStream_t stream) {
    const float* x      = (const float*)d_in[0];
    const int*   ei     = (const int*)d_in[1];
    const float* ea     = (const float*)d_in[2];
    const float* in_w   = (const float*)d_in[3];
    const float* in_b   = (const float*)d_in[4];
    const float* edge_w = (const float*)d_in[5];
    const float* edge_b = (const float*)d_in[6];
    const float* mlp_w1 = (const float*)d_in[7];
    const float* mlp_b1 = (const float*)d_in[8];
    const float* mlp_w2 = (const float*)d_in[9];
    const float* mlp_b2 = (const float*)d_in[10];
    const float* ln_g   = (const float*)d_in[11];
    const float* ln_b   = (const float*)d_in[12];
    const float* reg_w1 = (const float*)d_in[13];
    const float* reg_b1 = (const float*)d_in[14];
    const float* reg_w2 = (const float*)d_in[15];
    const float* reg_b2 = (const float*)d_in[16];

    char* ws = (char*)d_ws;
    unsigned short* hb0     = (unsigned short*)ws; ws += (size_t)N_NODES * 64 * 2;
    unsigned short* hb1     = (unsigned short*)ws; ws += (size_t)N_NODES * 64 * 2;
    unsigned short* zb      = (unsigned short*)ws; ws += (size_t)N_NODES * 64 * 2;
    unsigned char*  hf8_0   = (unsigned char*)ws;  ws += (size_t)N_NODES * 64;
    unsigned char*  hf8_1   = (unsigned char*)ws;  ws += (size_t)N_NODES * 64;
    int4*           rec     = (int4*)ws;           ws += (size_t)N_EDGES * 16;
    unsigned short* fin     = (unsigned short*)ws; ws += 12288 * 2;
    unsigned short* f1      = (unsigned short*)ws; ws += 32768 * 2;
    unsigned short* f2      = (unsigned short*)ws; ws += 32768 * 2;
    int*            erank   = (int*)ws;            ws += (size_t)N_EDGES * 4;
    int*            row_ptr = (int*)ws;            ws += (size_t)(N_NODES + 1) * 4;
    int*            cnt     = (int*)ws;            ws += (size_t)N_NODES * 16 * 4;  // padded: 1 counter / 64B
    int*            blksum  = (int*)ws;            ws += SCAN_NB * 4;
    float*          gpart   = (float*)ws;          ws += 256 * 64 * 4;
    float*          outf    = (float*)d_out;

    const int eb_blocks = (N_EDGES + 255) / 256;

    k_wprep<<<304, 256, 0, stream>>>(in_w, mlp_w1, mlp_w2, fin, f1, f2, cnt);

    k_hist<<<eb_blocks, 256, 0, stream>>>(ei, cnt, erank);
    k_scan_part<<<SCAN_NB, 256, 0, stream>>>(cnt, blksum);
    k_scan_add<<<SCAN_NB, 256, 0, stream>>>(cnt, blksum, row_ptr);
    k_scatter<<<eb_blocks, 256, 0, stream>>>(ei, (const float4*)ea, row_ptr, erank, rec);

    k_inproj_mfma<<<512, 256, 0, stream>>>(x, fin, in_b, hb0, hf8_0);

    unsigned short* hbA = hb0;
    unsigned short* hbB = hb1;
    unsigned char*  hfA = hf8_0;
    unsigned char*  hfB = hf8_1;
    for (int l = 0; l < 4; ++l) {
        k_aggr<<<N_NODES / 4, 256, 0, stream>>>(hbA, hfA, zb, row_ptr, rec,
                                                edge_w + l * 4 * 64,
                                                edge_b + l * 64);
        k_mlp_mfma<<<768, 256, 0, stream>>>(zb, hbB, hfB,
                                            f1 + l * 8192, f2 + l * 8192,
                                            mlp_b1 + l * 128, mlp_b2 + l * 64,
                                            ln_g + l * 64, ln_b + l * 64);
        unsigned short* tb = hbA; hbA = hbB; hbB = tb;
        unsigned char*  tf = hfA; hfA = hfB; hfB = tf;
    }

    k_pool<<<256, 256, 0, stream>>>(hbA, gpart);
    k_reg<<<1, 64, 0, stream>>>(gpart, reg_w1, reg_b1, reg_w2, reg_b2, outf);
}